// Round 1
// baseline (1570.336 us; speedup 1.0000x reference)
//
#include <hip/hip_runtime.h>
#include <math.h>

#define NN 100000
#define EE 3200000
#define FF 128
#define HH 16
#define CC 10
#define KK1 25000
#define KK2 6250

struct SelState {
  unsigned prefix;
  unsigned kcur;
  unsigned ctr_gt;
  unsigned ctr_eq;
  unsigned hist[256];
};

__device__ __forceinline__ unsigned fkey(float f) {
  unsigned u = __float_as_uint(f);
  return (u & 0x80000000u) ? ~u : (u | 0x80000000u);
}

// ---------------- conv1: h0 = x @ W1  ([N,128] @ [128,16]) ----------------
__global__ __launch_bounds__(256) void k_xw1(const float* __restrict__ x,
                                             const float* __restrict__ W1,
                                             float* __restrict__ h0) {
  __shared__ float sW[FF * HH];     // 8 KB
  __shared__ float sx[16][FF];      // 8 KB
  int t = threadIdx.x;
  for (int i = t; i < FF * HH; i += 256) sW[i] = W1[i];
  int base = blockIdx.x * 16;
  for (int i = t; i < 16 * FF; i += 256) {
    int r = i >> 7, c = i & 127;
    int node = base + r;
    sx[r][c] = (node < NN) ? x[(size_t)node * FF + c] : 0.f;
  }
  __syncthreads();
  int r = t >> 4;   // node in tile
  int o = t & 15;   // output col
  float acc = 0.f;
#pragma unroll
  for (int k = 0; k < FF; ++k) acc += sx[r][k] * sW[k * HH + o];
  int node = base + r;
  if (node < NN) h0[node * HH + o] = acc;
}

// ---------------- generic helpers ----------------
__global__ void k_fill(float* __restrict__ p, int n, float v) {
  int i = blockIdx.x * blockDim.x + threadIdx.x;
  if (i < n) p[i] = v;
}

__global__ void k_rsqrt(float* __restrict__ p, int n) {
  int i = blockIdx.x * blockDim.x + threadIdx.x;
  if (i < n) p[i] = rsqrtf(p[i]);
}

// deg[dst] += 1 for every edge (ew0 == 1)
__global__ void k_deg_edges(const int* __restrict__ dst, float* __restrict__ deg) {
  int e = blockIdx.x * blockDim.x + threadIdx.x;
  if (e < EE) atomicAdd(&deg[dst[e]], 1.0f);
}

// agg[dst,k] += h0[src,k] * dinv[src]*dinv[dst]; 16 threads per edge
__global__ __launch_bounds__(256) void k_agg1(const float* __restrict__ h0,
                                              const float* __restrict__ dinv,
                                              const int* __restrict__ src,
                                              const int* __restrict__ dst,
                                              float* __restrict__ agg) {
  int tid = blockIdx.x * 256 + threadIdx.x;
  int e = tid >> 4;
  int k = tid & 15;
  if (e >= EE) return;
  int s = src[e], d = dst[e];
  float norm = dinv[s] * dinv[d];
  atomicAdd(&agg[d * HH + k], h0[s * HH + k] * norm);
}

template <int D, bool RELU>
__global__ void k_combine(const float* __restrict__ h0, const float* __restrict__ dinv,
                          const float* __restrict__ b, float* __restrict__ agg, int n) {
  int i = blockIdx.x * blockDim.x + threadIdx.x;
  if (i >= n * D) return;
  int node = i / D;
  int k = i - node * D;
  float di = dinv[node];
  float v = agg[i] + h0[i] * di * di + b[k];
  if (RELU) v = v > 0.f ? v : 0.f;
  agg[i] = v;
}

// score[i] = h[i]·wroot + b ; hrel[i] = h[i]·wrel
template <int D>
__global__ void k_score_init(const float* __restrict__ h, const float* __restrict__ wroot,
                             const float* __restrict__ wrel, const float* __restrict__ bp,
                             int n, float* __restrict__ score, float* __restrict__ hrel) {
  int i = blockIdx.x * blockDim.x + threadIdx.x;
  if (i >= n) return;
  float sr = 0.f, sl = 0.f;
#pragma unroll
  for (int k = 0; k < D; ++k) {
    float v = h[i * D + k];
    sr += v * wroot[k];
    sl += v * wrel[k];
  }
  score[i] = sr + bp[0];
  hrel[i] = sl;
}

// score[dst] += hrel[src] over all E edges (ew=1)
__global__ void k_score_edges1(const int* __restrict__ src, const int* __restrict__ dst,
                               const float* __restrict__ hrel, float* __restrict__ score) {
  int e = blockIdx.x * blockDim.x + threadIdx.x;
  if (e < EE) atomicAdd(&score[dst[e]], hrel[src[e]]);
}

// ---------------- radix top-k select ----------------
__global__ void k_state_init(SelState* st, int K) {
  if (threadIdx.x == 0) {
    st->prefix = 0;
    st->kcur = (unsigned)K;
    st->ctr_gt = 0;
    st->ctr_eq = 0;
  }
  st->hist[threadIdx.x] = 0;
}

__global__ __launch_bounds__(256) void k_hist(const float* __restrict__ vals, int n,
                                              SelState* st, int pass) {
  __shared__ unsigned sh[256];
  int t = threadIdx.x;
  sh[t] = 0;
  __syncthreads();
  int i = blockIdx.x * 256 + t;
  if (i < n) {
    unsigned key = fkey(vals[i]);
    bool ok = true;
    if (pass != 0) ok = (key >> (32 - 8 * pass)) == st->prefix;
    if (ok) atomicAdd(&sh[(key >> (24 - 8 * pass)) & 255], 1u);
  }
  __syncthreads();
  if (sh[t]) atomicAdd(&st->hist[t], sh[t]);
}

__global__ void k_scan(SelState* st) {
  unsigned kcur = st->kcur;
  unsigned cum = 0;
  int b = 255;
  for (; b >= 0; --b) {
    unsigned c = st->hist[b];
    if (cum + c >= kcur) break;
    cum += c;
  }
  st->prefix = (st->prefix << 8) | (unsigned)b;
  st->kcur = kcur - cum;
  for (int i = 0; i < 256; ++i) st->hist[i] = 0;
}

// pool1 selection: new_idx + gather-scale x1 = h[kept]*tanh(score)
__global__ void k_select1(const float* __restrict__ score, const float* __restrict__ h,
                          SelState* st, int* __restrict__ new_idx,
                          float* __restrict__ x1) {
  int i = blockIdx.x * blockDim.x + threadIdx.x;
  if (i >= NN) return;
  float sc = score[i];
  unsigned key = fkey(sc);
  unsigned T = st->prefix;
  int id = -1;
  if (key > T) {
    id = (int)atomicAdd(&st->ctr_gt, 1u);
  } else if (key == T) {
    unsigned p = atomicAdd(&st->ctr_eq, 1u);
    unsigned kneed = st->kcur;
    if (p < kneed) id = (KK1 - (int)kneed) + (int)p;
  }
  new_idx[i] = id;
  if (id >= 0) {
    float tv = tanhf(sc);
#pragma unroll
    for (int k = 0; k < HH; ++k) x1[id * HH + k] = h[i * HH + k] * tv;
  }
}

// compact surviving edges with relabeled endpoints
__global__ void k_compact(const int* __restrict__ src, const int* __restrict__ dst,
                          const int* __restrict__ new_idx, int* __restrict__ es,
                          int* __restrict__ ed, int* __restrict__ ecnt) {
  int e = blockIdx.x * blockDim.x + threadIdx.x;
  if (e >= EE) return;
  int s = new_idx[src[e]];
  int d = new_idx[dst[e]];
  if (s >= 0 && d >= 0) {
    int p = atomicAdd(ecnt, 1);
    es[p] = s;
    ed[p] = d;
  }
}

// ---------------- conv2 ----------------
__global__ void k_xw2(const float* __restrict__ x1, const float* __restrict__ W2,
                      float* __restrict__ h20) {
  int t = blockIdx.x * blockDim.x + threadIdx.x;
  if (t >= KK1 * CC) return;
  int node = t / CC;
  int o = t - node * CC;
  float acc = 0.f;
#pragma unroll
  for (int k = 0; k < HH; ++k) acc += x1[node * HH + k] * W2[k * CC + o];
  h20[t] = acc;
}

__global__ void k_deg2_edges(const int* __restrict__ ed, const int* __restrict__ ecnt,
                             float* __restrict__ deg) {
  int e = blockIdx.x * blockDim.x + threadIdx.x;
  if (e < *ecnt) atomicAdd(&deg[ed[e]], 1.0f);
}

__global__ void k_agg2(const float* __restrict__ h20, const float* __restrict__ dinv,
                       const int* __restrict__ es, const int* __restrict__ ed,
                       const int* __restrict__ ecnt, float* __restrict__ agg) {
  int e = blockIdx.x * blockDim.x + threadIdx.x;
  if (e >= *ecnt) return;
  int s = es[e], d = ed[e];
  float norm = dinv[s] * dinv[d];
#pragma unroll
  for (int k = 0; k < CC; ++k)
    atomicAdd(&agg[d * CC + k], h20[s * CC + k] * norm);
}

__global__ void k_score_edges2(const int* __restrict__ es, const int* __restrict__ ed,
                               const int* __restrict__ ecnt,
                               const float* __restrict__ hrel, float* __restrict__ score) {
  int e = blockIdx.x * blockDim.x + threadIdx.x;
  if (e < *ecnt) atomicAdd(&score[ed[e]], hrel[es[e]]);
}

// pool2 selection folded directly into the output accumulator
__global__ void k_final_accum(const float* __restrict__ score, const float* __restrict__ h2,
                              SelState* st, float* __restrict__ acc) {
  int i = blockIdx.x * blockDim.x + threadIdx.x;
  if (i >= KK1) return;
  float sc = score[i];
  unsigned key = fkey(sc);
  unsigned T = st->prefix;
  bool keep = false;
  if (key > T) {
    keep = true;
  } else if (key == T) {
    unsigned p = atomicAdd(&st->ctr_eq, 1u);
    keep = (p < st->kcur);
  }
  if (keep) {
    float tv = tanhf(sc);
#pragma unroll
    for (int c = 0; c < CC; ++c) atomicAdd(&acc[c], h2[i * CC + c] * tv);
  }
}

__global__ void k_final(const float* __restrict__ acc, float* __restrict__ out) {
  if (threadIdx.x != 0 || blockIdx.x != 0) return;
  float v[CC];
  float m = -1e30f;
#pragma unroll
  for (int c = 0; c < CC; ++c) {
    v[c] = acc[c] / (float)KK2;
    if (v[c] > m) m = v[c];
  }
  float s = 0.f;
#pragma unroll
  for (int c = 0; c < CC; ++c) s += expf(v[c] - m);
  float l = logf(s);
#pragma unroll
  for (int c = 0; c < CC; ++c) out[c] = v[c] - m - l;
}

// ---------------- driver ----------------
extern "C" void kernel_launch(void* const* d_in, const int* in_sizes, int n_in,
                              void* d_out, int out_size, void* d_ws, size_t ws_size,
                              hipStream_t stream) {
  const float* x      = (const float*)d_in[0];
  const int*   esrc   = (const int*)d_in[1];
  const int*   edst   = (const int*)d_in[2];
  const float* W1     = (const float*)d_in[3];
  const float* b1     = (const float*)d_in[4];
  const float* w1root = (const float*)d_in[5];
  const float* w1rel  = (const float*)d_in[6];
  const float* p1b    = (const float*)d_in[7];
  const float* W2     = (const float*)d_in[8];
  const float* b2     = (const float*)d_in[9];
  const float* w2root = (const float*)d_in[10];
  const float* w2rel  = (const float*)d_in[11];
  const float* p2b    = (const float*)d_in[12];
  float* out = (float*)d_out;

  char* w = (char*)d_ws;
  size_t off = 0;
  auto alloc = [&](size_t bytes) -> char* {
    char* p = w + off;
    off += (bytes + 255) & ~(size_t)255;
    return p;
  };
  float* h0     = (float*)alloc((size_t)NN * HH * 4);
  float* hbuf   = (float*)alloc((size_t)NN * HH * 4);   // agg then h (post-relu)
  float* dinv1  = (float*)alloc((size_t)NN * 4);        // deg then rsqrt in place
  float* hrel1  = (float*)alloc((size_t)NN * 4);
  float* score1 = (float*)alloc((size_t)NN * 4);
  int*   nidx   = (int*)  alloc((size_t)NN * 4);
  float* x1     = (float*)alloc((size_t)KK1 * HH * 4);
  int*   es     = (int*)  alloc((size_t)EE * 4);
  int*   ed     = (int*)  alloc((size_t)EE * 4);
  float* h20    = (float*)alloc((size_t)KK1 * CC * 4);
  float* h2     = (float*)alloc((size_t)KK1 * CC * 4);  // agg2 then h2 in place
  float* dinv2  = (float*)alloc((size_t)KK1 * 4);
  float* h2rel  = (float*)alloc((size_t)KK1 * 4);
  float* score2 = (float*)alloc((size_t)KK1 * 4);
  SelState* st1 = (SelState*)alloc(sizeof(SelState));
  SelState* st2 = (SelState*)alloc(sizeof(SelState));
  int*   ecnt   = (int*)  alloc(256);
  float* acc    = (float*)alloc(256);

  const int BN   = (NN + 255) / 256;        // 391
  const int BE   = EE / 256;                // 12500
  const int BK1  = (KK1 + 255) / 256;       // 98

  // ---- conv1 + relu ----
  k_xw1<<<NN / 16, 256, 0, stream>>>(x, W1, h0);
  k_fill<<<BN, 256, 0, stream>>>(dinv1, NN, 1.0f);               // deg = 1 (self-loop)
  k_deg_edges<<<BE, 256, 0, stream>>>(edst, dinv1);
  k_rsqrt<<<BN, 256, 0, stream>>>(dinv1, NN);
  hipMemsetAsync(hbuf, 0, (size_t)NN * HH * 4, stream);
  k_agg1<<<(EE * HH) / 256, 256, 0, stream>>>(h0, dinv1, esrc, edst, hbuf);
  k_combine<HH, true><<<(NN * HH) / 256, 256, 0, stream>>>(h0, dinv1, b1, hbuf, NN);

  // ---- pool1 score ----
  k_score_init<HH><<<BN, 256, 0, stream>>>(hbuf, w1root, w1rel, p1b, NN, score1, hrel1);
  k_score_edges1<<<BE, 256, 0, stream>>>(esrc, edst, hrel1, score1);

  // ---- pool1 top-k (radix select) ----
  k_state_init<<<1, 256, 0, stream>>>(st1, KK1);
  for (int p = 0; p < 4; ++p) {
    k_hist<<<BN, 256, 0, stream>>>(score1, NN, st1, p);
    k_scan<<<1, 1, 0, stream>>>(st1);
  }
  k_select1<<<BN, 256, 0, stream>>>(score1, hbuf, st1, nidx, x1);
  hipMemsetAsync(ecnt, 0, 4, stream);
  k_compact<<<BE, 256, 0, stream>>>(esrc, edst, nidx, es, ed, ecnt);

  // ---- conv2 (no relu) ----
  k_xw2<<<(KK1 * CC + 255) / 256, 256, 0, stream>>>(x1, W2, h20);
  k_fill<<<BK1, 256, 0, stream>>>(dinv2, KK1, 1.0f);
  k_deg2_edges<<<BE, 256, 0, stream>>>(ed, ecnt, dinv2);
  k_rsqrt<<<BK1, 256, 0, stream>>>(dinv2, KK1);
  hipMemsetAsync(h2, 0, (size_t)KK1 * CC * 4, stream);
  k_agg2<<<BE, 256, 0, stream>>>(h20, dinv2, es, ed, ecnt, h2);
  k_combine<CC, false><<<(KK1 * CC + 255) / 256, 256, 0, stream>>>(h20, dinv2, b2, h2, KK1);

  // ---- pool2 score ----
  k_score_init<CC><<<BK1, 256, 0, stream>>>(h2, w2root, w2rel, p2b, KK1, score2, h2rel);
  k_score_edges2<<<BE, 256, 0, stream>>>(es, ed, ecnt, h2rel, score2);

  // ---- pool2 top-k + mean + log_softmax ----
  k_state_init<<<1, 256, 0, stream>>>(st2, KK2);
  for (int p = 0; p < 4; ++p) {
    k_hist<<<BK1, 256, 0, stream>>>(score2, KK1, st2, p);
    k_scan<<<1, 1, 0, stream>>>(st2);
  }
  hipMemsetAsync(acc, 0, CC * 4, stream);
  k_final_accum<<<BK1, 256, 0, stream>>>(score2, h2, st2, acc);
  k_final<<<1, 64, 0, stream>>>(acc, out);
}

// Round 2
// 1143.682 us; speedup vs baseline: 1.3731x; 1.3731x over previous
//
#include <hip/hip_runtime.h>
#include <math.h>

#define NN 100000
#define EE 3200000
#define FF 128
#define HH 16
#define CC 10
#define KK1 25000
#define KK2 6250

struct SelState {
  unsigned prefix;
  unsigned kcur;
  unsigned ctr_gt;
  unsigned ctr_eq;
  unsigned hist[256];
};

__device__ __forceinline__ unsigned fkey(float f) {
  unsigned u = __float_as_uint(f);
  return (u & 0x80000000u) ? ~u : (u | 0x80000000u);
}

// ---------------- conv1: h0 = x @ W1  ([N,128] @ [128,16]) ----------------
__global__ __launch_bounds__(256) void k_xw1(const float* __restrict__ x,
                                             const float* __restrict__ W1,
                                             float* __restrict__ h0) {
  __shared__ float sW[FF * HH];     // 8 KB
  __shared__ float sx[16][FF];      // 8 KB
  int t = threadIdx.x;
  for (int i = t; i < FF * HH; i += 256) sW[i] = W1[i];
  int base = blockIdx.x * 16;
  for (int i = t; i < 16 * FF; i += 256) {
    int r = i >> 7, c = i & 127;
    int node = base + r;
    sx[r][c] = (node < NN) ? x[(size_t)node * FF + c] : 0.f;
  }
  __syncthreads();
  int r = t >> 4;   // node in tile
  int o = t & 15;   // output col
  float acc = 0.f;
#pragma unroll
  for (int k = 0; k < FF; ++k) acc += sx[r][k] * sW[k * HH + o];
  int node = base + r;
  if (node < NN) h0[node * HH + o] = acc;
}

// ---------------- generic helpers ----------------
__global__ void k_fill(float* __restrict__ p, int n, float v) {
  int i = blockIdx.x * blockDim.x + threadIdx.x;
  if (i < n) p[i] = v;
}

__global__ void k_rsqrt(float* __restrict__ p, int n) {
  int i = blockIdx.x * blockDim.x + threadIdx.x;
  if (i < n) p[i] = rsqrtf(p[i]);
}

// deg[dst] += 1 for every edge (ew0 == 1)
__global__ void k_deg_edges(const int* __restrict__ dst, float* __restrict__ deg) {
  int e = blockIdx.x * blockDim.x + threadIdx.x;
  if (e < EE) atomicAdd(&deg[dst[e]], 1.0f);
}

// agg[dst,k] += h0[src,k] * dinv[src]*dinv[dst]; 16 threads per edge
__global__ __launch_bounds__(256) void k_agg1(const float* __restrict__ h0,
                                              const float* __restrict__ dinv,
                                              const int* __restrict__ src,
                                              const int* __restrict__ dst,
                                              float* __restrict__ agg) {
  int tid = blockIdx.x * 256 + threadIdx.x;
  int e = tid >> 4;
  int k = tid & 15;
  if (e >= EE) return;
  int s = src[e], d = dst[e];
  float norm = dinv[s] * dinv[d];
  atomicAdd(&agg[d * HH + k], h0[s * HH + k] * norm);
}

template <int D, bool RELU>
__global__ void k_combine(const float* __restrict__ h0, const float* __restrict__ dinv,
                          const float* __restrict__ b, float* __restrict__ agg, int n) {
  int i = blockIdx.x * blockDim.x + threadIdx.x;
  if (i >= n * D) return;
  int node = i / D;
  int k = i - node * D;
  float di = dinv[node];
  float v = agg[i] + h0[i] * di * di + b[k];
  if (RELU) v = v > 0.f ? v : 0.f;
  agg[i] = v;
}

// score[i] = h[i]·wroot + b ; hrel[i] = h[i]·wrel
template <int D>
__global__ void k_score_init(const float* __restrict__ h, const float* __restrict__ wroot,
                             const float* __restrict__ wrel, const float* __restrict__ bp,
                             int n, float* __restrict__ score, float* __restrict__ hrel) {
  int i = blockIdx.x * blockDim.x + threadIdx.x;
  if (i >= n) return;
  float sr = 0.f, sl = 0.f;
#pragma unroll
  for (int k = 0; k < D; ++k) {
    float v = h[i * D + k];
    sr += v * wroot[k];
    sl += v * wrel[k];
  }
  score[i] = sr + bp[0];
  hrel[i] = sl;
}

// score[dst] += hrel[src] over all E edges (ew=1)
__global__ void k_score_edges1(const int* __restrict__ src, const int* __restrict__ dst,
                               const float* __restrict__ hrel, float* __restrict__ score) {
  int e = blockIdx.x * blockDim.x + threadIdx.x;
  if (e < EE) atomicAdd(&score[dst[e]], hrel[src[e]]);
}

// ---------------- radix top-k select ----------------
__global__ void k_state_init(SelState* st, int K) {
  if (threadIdx.x == 0) {
    st->prefix = 0;
    st->kcur = (unsigned)K;
    st->ctr_gt = 0;
    st->ctr_eq = 0;
  }
  st->hist[threadIdx.x] = 0;
}

__global__ __launch_bounds__(256) void k_hist(const float* __restrict__ vals, int n,
                                              SelState* st, int pass) {
  __shared__ unsigned sh[256];
  int t = threadIdx.x;
  sh[t] = 0;
  __syncthreads();
  int i = blockIdx.x * 256 + t;
  if (i < n) {
    unsigned key = fkey(vals[i]);
    bool ok = true;
    if (pass != 0) ok = (key >> (32 - 8 * pass)) == st->prefix;
    if (ok) atomicAdd(&sh[(key >> (24 - 8 * pass)) & 255], 1u);
  }
  __syncthreads();
  if (sh[t]) atomicAdd(&st->hist[t], sh[t]);
}

__global__ void k_scan(SelState* st) {
  unsigned kcur = st->kcur;
  unsigned cum = 0;
  int b = 255;
  for (; b >= 0; --b) {
    unsigned c = st->hist[b];
    if (cum + c >= kcur) break;
    cum += c;
  }
  st->prefix = (st->prefix << 8) | (unsigned)b;
  st->kcur = kcur - cum;
  for (int i = 0; i < 256; ++i) st->hist[i] = 0;
}

// pool1 selection: new_idx + gather-scale x1 = h[kept]*tanh(score)
__global__ void k_select1(const float* __restrict__ score, const float* __restrict__ h,
                          SelState* st, int* __restrict__ new_idx,
                          float* __restrict__ x1) {
  int i = blockIdx.x * blockDim.x + threadIdx.x;
  if (i >= NN) return;
  float sc = score[i];
  unsigned key = fkey(sc);
  unsigned T = st->prefix;
  int id = -1;
  if (key > T) {
    id = (int)atomicAdd(&st->ctr_gt, 1u);
  } else if (key == T) {
    unsigned p = atomicAdd(&st->ctr_eq, 1u);
    unsigned kneed = st->kcur;
    if (p < kneed) id = (KK1 - (int)kneed) + (int)p;
  }
  new_idx[i] = id;
  if (id >= 0) {
    float tv = tanhf(sc);
#pragma unroll
    for (int k = 0; k < HH; ++k) x1[id * HH + k] = h[i * HH + k] * tv;
  }
}

// compact surviving edges with relabeled endpoints.
// Hierarchical counter: wave ballot -> block LDS sum -> ONE global atomic/block.
// Also fuses the deg2 histogram (deg2 pre-filled to 1.0 for self-loop).
__global__ __launch_bounds__(256) void k_compact(const int* __restrict__ src,
                                                 const int* __restrict__ dst,
                                                 const int* __restrict__ new_idx,
                                                 int* __restrict__ es,
                                                 int* __restrict__ ed,
                                                 int* __restrict__ ecnt,
                                                 float* __restrict__ deg2) {
  int e = blockIdx.x * blockDim.x + threadIdx.x;
  int s = 0, d = 0;
  bool valid = false;
  if (e < EE) {
    s = new_idx[src[e]];
    d = new_idx[dst[e]];
    valid = (s >= 0 && d >= 0);
  }
  unsigned long long mask = __ballot(valid);
  int lane = threadIdx.x & 63;
  int wid = threadIdx.x >> 6;
  __shared__ int wbase[4];
  if (lane == 0) wbase[wid] = __popcll(mask);
  __syncthreads();
  if (threadIdx.x == 0) {
    int tot = wbase[0] + wbase[1] + wbase[2] + wbase[3];
    int base = atomicAdd(ecnt, tot);
    int b = base;
    for (int i = 0; i < 4; ++i) { int c = wbase[i]; wbase[i] = b; b += c; }
  }
  __syncthreads();
  if (valid) {
    int pos = wbase[wid] + __popcll(mask & ((1ull << lane) - 1ull));
    es[pos] = s;
    ed[pos] = d;
    atomicAdd(&deg2[d], 1.0f);
  }
}

// ---------------- conv2 ----------------
__global__ void k_xw2(const float* __restrict__ x1, const float* __restrict__ W2,
                      float* __restrict__ h20) {
  int t = blockIdx.x * blockDim.x + threadIdx.x;
  if (t >= KK1 * CC) return;
  int node = t / CC;
  int o = t - node * CC;
  float acc = 0.f;
#pragma unroll
  for (int k = 0; k < HH; ++k) acc += x1[node * HH + k] * W2[k * CC + o];
  h20[t] = acc;
}

__global__ void k_agg2(const float* __restrict__ h20, const float* __restrict__ dinv,
                       const int* __restrict__ es, const int* __restrict__ ed,
                       const int* __restrict__ ecnt, float* __restrict__ agg) {
  int e = blockIdx.x * blockDim.x + threadIdx.x;
  if (e >= *ecnt) return;
  int s = es[e], d = ed[e];
  float norm = dinv[s] * dinv[d];
#pragma unroll
  for (int k = 0; k < CC; ++k)
    atomicAdd(&agg[d * CC + k], h20[s * CC + k] * norm);
}

__global__ void k_score_edges2(const int* __restrict__ es, const int* __restrict__ ed,
                               const int* __restrict__ ecnt,
                               const float* __restrict__ hrel, float* __restrict__ score) {
  int e = blockIdx.x * blockDim.x + threadIdx.x;
  if (e < *ecnt) atomicAdd(&score[ed[e]], hrel[es[e]]);
}

// pool2 selection folded directly into the output accumulator
__global__ void k_final_accum(const float* __restrict__ score, const float* __restrict__ h2,
                              SelState* st, float* __restrict__ acc) {
  int i = blockIdx.x * blockDim.x + threadIdx.x;
  if (i >= KK1) return;
  float sc = score[i];
  unsigned key = fkey(sc);
  unsigned T = st->prefix;
  bool keep = false;
  if (key > T) {
    keep = true;
  } else if (key == T) {
    unsigned p = atomicAdd(&st->ctr_eq, 1u);
    keep = (p < st->kcur);
  }
  if (keep) {
    float tv = tanhf(sc);
#pragma unroll
    for (int c = 0; c < CC; ++c) atomicAdd(&acc[c], h2[i * CC + c] * tv);
  }
}

__global__ void k_final(const float* __restrict__ acc, float* __restrict__ out) {
  if (threadIdx.x != 0 || blockIdx.x != 0) return;
  float v[CC];
  float m = -1e30f;
#pragma unroll
  for (int c = 0; c < CC; ++c) {
    v[c] = acc[c] / (float)KK2;
    if (v[c] > m) m = v[c];
  }
  float s = 0.f;
#pragma unroll
  for (int c = 0; c < CC; ++c) s += expf(v[c] - m);
  float l = logf(s);
#pragma unroll
  for (int c = 0; c < CC; ++c) out[c] = v[c] - m - l;
}

// ---------------- driver ----------------
extern "C" void kernel_launch(void* const* d_in, const int* in_sizes, int n_in,
                              void* d_out, int out_size, void* d_ws, size_t ws_size,
                              hipStream_t stream) {
  const float* x      = (const float*)d_in[0];
  const int*   esrc   = (const int*)d_in[1];
  const int*   edst   = (const int*)d_in[2];
  const float* W1     = (const float*)d_in[3];
  const float* b1     = (const float*)d_in[4];
  const float* w1root = (const float*)d_in[5];
  const float* w1rel  = (const float*)d_in[6];
  const float* p1b    = (const float*)d_in[7];
  const float* W2     = (const float*)d_in[8];
  const float* b2     = (const float*)d_in[9];
  const float* w2root = (const float*)d_in[10];
  const float* w2rel  = (const float*)d_in[11];
  const float* p2b    = (const float*)d_in[12];
  float* out = (float*)d_out;

  char* w = (char*)d_ws;
  size_t off = 0;
  auto alloc = [&](size_t bytes) -> char* {
    char* p = w + off;
    off += (bytes + 255) & ~(size_t)255;
    return p;
  };
  float* h0     = (float*)alloc((size_t)NN * HH * 4);
  float* hbuf   = (float*)alloc((size_t)NN * HH * 4);   // agg then h (post-relu)
  float* dinv1  = (float*)alloc((size_t)NN * 4);        // deg then rsqrt in place
  float* hrel1  = (float*)alloc((size_t)NN * 4);
  float* score1 = (float*)alloc((size_t)NN * 4);
  int*   nidx   = (int*)  alloc((size_t)NN * 4);
  float* x1     = (float*)alloc((size_t)KK1 * HH * 4);
  int*   es     = (int*)  alloc((size_t)EE * 4);
  int*   ed     = (int*)  alloc((size_t)EE * 4);
  float* h20    = (float*)alloc((size_t)KK1 * CC * 4);
  float* h2     = (float*)alloc((size_t)KK1 * CC * 4);  // agg2 then h2 in place
  float* dinv2  = (float*)alloc((size_t)KK1 * 4);
  float* h2rel  = (float*)alloc((size_t)KK1 * 4);
  float* score2 = (float*)alloc((size_t)KK1 * 4);
  SelState* st1 = (SelState*)alloc(sizeof(SelState));
  SelState* st2 = (SelState*)alloc(sizeof(SelState));
  int*   ecnt   = (int*)  alloc(256);
  float* acc    = (float*)alloc(256);

  const int BN   = (NN + 255) / 256;        // 391
  const int BE   = EE / 256;                // 12500
  const int BK1  = (KK1 + 255) / 256;       // 98

  // ---- conv1 + relu ----
  k_xw1<<<NN / 16, 256, 0, stream>>>(x, W1, h0);
  k_fill<<<BN, 256, 0, stream>>>(dinv1, NN, 1.0f);               // deg = 1 (self-loop)
  k_deg_edges<<<BE, 256, 0, stream>>>(edst, dinv1);
  k_rsqrt<<<BN, 256, 0, stream>>>(dinv1, NN);
  hipMemsetAsync(hbuf, 0, (size_t)NN * HH * 4, stream);
  k_agg1<<<(EE * HH) / 256, 256, 0, stream>>>(h0, dinv1, esrc, edst, hbuf);
  k_combine<HH, true><<<(NN * HH) / 256, 256, 0, stream>>>(h0, dinv1, b1, hbuf, NN);

  // ---- pool1 score ----
  k_score_init<HH><<<BN, 256, 0, stream>>>(hbuf, w1root, w1rel, p1b, NN, score1, hrel1);
  k_score_edges1<<<BE, 256, 0, stream>>>(esrc, edst, hrel1, score1);

  // ---- pool1 top-k (radix select) ----
  k_state_init<<<1, 256, 0, stream>>>(st1, KK1);
  for (int p = 0; p < 4; ++p) {
    k_hist<<<BN, 256, 0, stream>>>(score1, NN, st1, p);
    k_scan<<<1, 1, 0, stream>>>(st1);
  }
  k_select1<<<BN, 256, 0, stream>>>(score1, hbuf, st1, nidx, x1);

  // ---- edge compaction (+deg2 fused; dinv2 pre-filled to 1.0 self-loop) ----
  hipMemsetAsync(ecnt, 0, 4, stream);
  k_fill<<<BK1, 256, 0, stream>>>(dinv2, KK1, 1.0f);
  k_compact<<<BE, 256, 0, stream>>>(esrc, edst, nidx, es, ed, ecnt, dinv2);

  // ---- conv2 (no relu) ----
  k_xw2<<<(KK1 * CC + 255) / 256, 256, 0, stream>>>(x1, W2, h20);
  k_rsqrt<<<BK1, 256, 0, stream>>>(dinv2, KK1);
  hipMemsetAsync(h2, 0, (size_t)KK1 * CC * 4, stream);
  k_agg2<<<BE, 256, 0, stream>>>(h20, dinv2, es, ed, ecnt, h2);
  k_combine<CC, false><<<(KK1 * CC + 255) / 256, 256, 0, stream>>>(h20, dinv2, b2, h2, KK1);

  // ---- pool2 score ----
  k_score_init<CC><<<BK1, 256, 0, stream>>>(h2, w2root, w2rel, p2b, KK1, score2, h2rel);
  k_score_edges2<<<BE, 256, 0, stream>>>(es, ed, ecnt, h2rel, score2);

  // ---- pool2 top-k + mean + log_softmax ----
  k_state_init<<<1, 256, 0, stream>>>(st2, KK2);
  for (int p = 0; p < 4; ++p) {
    k_hist<<<BK1, 256, 0, stream>>>(score2, KK1, st2, p);
    k_scan<<<1, 1, 0, stream>>>(st2);
  }
  hipMemsetAsync(acc, 0, CC * 4, stream);
  k_final_accum<<<BK1, 256, 0, stream>>>(score2, h2, st2, acc);
  k_final<<<1, 64, 0, stream>>>(acc, out);
}

// Round 3
// 883.319 us; speedup vs baseline: 1.7778x; 1.2948x over previous
//
#include <hip/hip_runtime.h>
#include <math.h>

#define NN 100000
#define EE 3200000
#define FF 128
#define HH 16
#define CC 10
#define KK1 25000
#define KK2 6250

struct SelState {
  unsigned prefix;
  unsigned kcur;
  unsigned ctr_gt;
  unsigned ctr_eq;
  unsigned hist[256];
};

__device__ __forceinline__ unsigned fkey(float f) {
  unsigned u = __float_as_uint(f);
  return (u & 0x80000000u) ? ~u : (u | 0x80000000u);
}

// ---------------- conv1 GEMM: h0 = x @ W1  ([N,128] @ [128,16]) ----------------
__global__ __launch_bounds__(256) void k_xw1(const float* __restrict__ x,
                                             const float* __restrict__ W1,
                                             float* __restrict__ h0) {
  __shared__ float sW[FF * HH];     // 8 KB
  __shared__ float sx[16][FF];      // 8 KB
  int t = threadIdx.x;
  for (int i = t; i < FF * HH; i += 256) sW[i] = W1[i];
  int base = blockIdx.x * 16;
  for (int i = t; i < 16 * FF; i += 256) {
    int r = i >> 7, c = i & 127;
    int node = base + r;
    sx[r][c] = (node < NN) ? x[(size_t)node * FF + c] : 0.f;
  }
  __syncthreads();
  int r = t >> 4;   // node in tile
  int o = t & 15;   // output col
  float acc = 0.f;
#pragma unroll
  for (int k = 0; k < FF; ++k) acc += sx[r][k] * sW[k * HH + o];
  int node = base + r;
  if (node < NN) h0[node * HH + o] = acc;
}

// ---------------- generic helpers ----------------
__global__ void k_fill(float* __restrict__ p, int n, float v) {
  int i = blockIdx.x * blockDim.x + threadIdx.x;
  if (i < n) p[i] = v;
}

__global__ void k_rsqrt(float* __restrict__ p, int n) {
  int i = blockIdx.x * blockDim.x + threadIdx.x;
  if (i < n) p[i] = rsqrtf(p[i]);
}

// ---------------- CSR build (by dst) ----------------
// returning atomic: rank[e] = old count (edge's slot within its dst segment)
__global__ void k_edge_hist(const int* __restrict__ dst, int* __restrict__ cnt,
                            int* __restrict__ rank) {
  int e = blockIdx.x * 256 + threadIdx.x;
  if (e < EE) rank[e] = atomicAdd(&cnt[dst[e]], 1);
}

__global__ __launch_bounds__(256) void k_scan1(const int* __restrict__ cnt,
                                               int* __restrict__ rowstart,
                                               int* __restrict__ bsum) {
  __shared__ int s[256];
  int t = threadIdx.x;
  int i = blockIdx.x * 256 + t;
  int v = (i < NN) ? cnt[i] : 0;
  s[t] = v;
  __syncthreads();
  for (int off = 1; off < 256; off <<= 1) {
    int u = (t >= off) ? s[t - off] : 0;
    __syncthreads();
    s[t] += u;
    __syncthreads();
  }
  if (i < NN) rowstart[i] = s[t] - v;   // exclusive
  if (t == 255) bsum[blockIdx.x] = s[255];
}

__global__ __launch_bounds__(512) void k_scan2(int* __restrict__ bsum, int n) {
  __shared__ int s[512];
  int t = threadIdx.x;
  int v = (t < n) ? bsum[t] : 0;
  s[t] = v;
  __syncthreads();
  for (int off = 1; off < 512; off <<= 1) {
    int u = (t >= off) ? s[t - off] : 0;
    __syncthreads();
    s[t] += u;
    __syncthreads();
  }
  if (t < n) bsum[t] = s[t] - v;        // exclusive
}

__global__ void k_scan3(int* __restrict__ rowstart, const int* __restrict__ bsum,
                        const int* __restrict__ cnt, float* __restrict__ dinv) {
  int i = blockIdx.x * 256 + threadIdx.x;
  if (i == 0) rowstart[NN] = EE;
  if (i < NN) {
    rowstart[i] += bsum[blockIdx.x];
    dinv[i] = rsqrtf((float)cnt[i] + 1.0f);   // deg = cnt + 1 (self-loop)
  }
}

__global__ void k_scatter(const int* __restrict__ src, const int* __restrict__ dst,
                          const int* __restrict__ rank, const int* __restrict__ rowstart,
                          int* __restrict__ csr) {
  int e = blockIdx.x * 256 + threadIdx.x;
  if (e < EE) csr[rowstart[dst[e]] + rank[e]] = src[e];
}

// ---------------- conv1 gather + self-loop + bias + relu + score init ----------------
// 16 threads per node (one per feature); shfl-broadcast csr/dinv; shfl-reduce scores.
__global__ __launch_bounds__(256) void k_conv1(const float* __restrict__ h0,
                                               const float* __restrict__ dinv,
                                               const int* __restrict__ rowstart,
                                               const int* __restrict__ csr,
                                               const float* __restrict__ b1,
                                               const float* __restrict__ wroot,
                                               const float* __restrict__ wrel,
                                               const float* __restrict__ bp,
                                               float* __restrict__ h,
                                               float* __restrict__ score,
                                               float* __restrict__ hrel) {
  int node = blockIdx.x * 16 + (threadIdx.x >> 4);
  int k = threadIdx.x & 15;
  int s0 = rowstart[node], s1 = rowstart[node + 1];
  float acc = 0.f;
  for (int base = s0; base < s1; base += 16) {
    int idx = base + k;
    int sv = (idx < s1) ? csr[idx] : 0;
    float dv = (idx < s1) ? dinv[sv] : 0.f;
    int m = min(16, s1 - base);
    for (int j = 0; j < m; ++j) {
      int s = __shfl(sv, j, 16);
      float d = __shfl(dv, j, 16);
      acc += h0[s * HH + k] * d;      // coalesced 64B row per step
    }
  }
  float di = dinv[node];
  float v = acc * di + h0[node * HH + k] * di * di + b1[k];
  v = v > 0.f ? v : 0.f;
  h[node * HH + k] = v;
  float sr = v * wroot[k];
  float sl = v * wrel[k];
#pragma unroll
  for (int m = 8; m; m >>= 1) {
    sr += __shfl_xor(sr, m, 16);
    sl += __shfl_xor(sl, m, 16);
  }
  if (k == 0) {
    score[node] = sr + bp[0];
    hrel[node] = sl;
  }
}

// score[d] += sum over in-edges of hrel[src]; 8 threads per node, no atomics
__global__ __launch_bounds__(256) void k_scoreg(const int* __restrict__ rowstart,
                                                const int* __restrict__ csr,
                                                const float* __restrict__ hrel,
                                                float* __restrict__ score) {
  int node = blockIdx.x * 32 + (threadIdx.x >> 3);
  int lane = threadIdx.x & 7;
  int s0 = rowstart[node], s1 = rowstart[node + 1];
  float sum = 0.f;
  for (int e = s0 + lane; e < s1; e += 8) sum += hrel[csr[e]];
#pragma unroll
  for (int m = 4; m; m >>= 1) sum += __shfl_xor(sum, m, 8);
  if (lane == 0) score[node] += sum;
}

// ---------------- radix top-k select ----------------
__global__ void k_state_init(SelState* st, int K) {
  if (threadIdx.x == 0) {
    st->prefix = 0;
    st->kcur = (unsigned)K;
    st->ctr_gt = 0;
    st->ctr_eq = 0;
  }
  st->hist[threadIdx.x] = 0;
}

__global__ __launch_bounds__(256) void k_hist(const float* __restrict__ vals, int n,
                                              SelState* st, int pass) {
  __shared__ unsigned sh[256];
  int t = threadIdx.x;
  sh[t] = 0;
  __syncthreads();
  int i = blockIdx.x * 256 + t;
  if (i < n) {
    unsigned key = fkey(vals[i]);
    bool ok = true;
    if (pass != 0) ok = (key >> (32 - 8 * pass)) == st->prefix;
    if (ok) atomicAdd(&sh[(key >> (24 - 8 * pass)) & 255], 1u);
  }
  __syncthreads();
  if (sh[t]) atomicAdd(&st->hist[t], sh[t]);
}

__global__ void k_scan(SelState* st) {
  unsigned kcur = st->kcur;
  unsigned cum = 0;
  int b = 255;
  for (; b >= 0; --b) {
    unsigned c = st->hist[b];
    if (cum + c >= kcur) break;
    cum += c;
  }
  st->prefix = (st->prefix << 8) | (unsigned)b;
  st->kcur = kcur - cum;
  for (int i = 0; i < 256; ++i) st->hist[i] = 0;
}

// pool1 selection: new_idx + gather-scale x1 = h[kept]*tanh(score)
__global__ void k_select1(const float* __restrict__ score, const float* __restrict__ h,
                          SelState* st, int* __restrict__ new_idx,
                          float* __restrict__ x1) {
  int i = blockIdx.x * blockDim.x + threadIdx.x;
  if (i >= NN) return;
  float sc = score[i];
  unsigned key = fkey(sc);
  unsigned T = st->prefix;
  int id = -1;
  if (key > T) {
    id = (int)atomicAdd(&st->ctr_gt, 1u);
  } else if (key == T) {
    unsigned p = atomicAdd(&st->ctr_eq, 1u);
    unsigned kneed = st->kcur;
    if (p < kneed) id = (KK1 - (int)kneed) + (int)p;
  }
  new_idx[i] = id;
  if (id >= 0) {
    float tv = tanhf(sc);
#pragma unroll
    for (int k = 0; k < HH; ++k) x1[id * HH + k] = h[i * HH + k] * tv;
  }
}

// compact surviving edges; hierarchical counter (1 global atomic/block); deg2 fused
__global__ __launch_bounds__(256) void k_compact(const int* __restrict__ src,
                                                 const int* __restrict__ dst,
                                                 const int* __restrict__ new_idx,
                                                 int* __restrict__ es,
                                                 int* __restrict__ ed,
                                                 int* __restrict__ ecnt,
                                                 float* __restrict__ deg2) {
  int e = blockIdx.x * blockDim.x + threadIdx.x;
  int s = 0, d = 0;
  bool valid = false;
  if (e < EE) {
    s = new_idx[src[e]];
    d = new_idx[dst[e]];
    valid = (s >= 0 && d >= 0);
  }
  unsigned long long mask = __ballot(valid);
  int lane = threadIdx.x & 63;
  int wid = threadIdx.x >> 6;
  __shared__ int wbase[4];
  if (lane == 0) wbase[wid] = __popcll(mask);
  __syncthreads();
  if (threadIdx.x == 0) {
    int tot = wbase[0] + wbase[1] + wbase[2] + wbase[3];
    int base = atomicAdd(ecnt, tot);
    int b = base;
    for (int i = 0; i < 4; ++i) { int c = wbase[i]; wbase[i] = b; b += c; }
  }
  __syncthreads();
  if (valid) {
    int pos = wbase[wid] + __popcll(mask & ((1ull << lane) - 1ull));
    es[pos] = s;
    ed[pos] = d;
    atomicAdd(&deg2[d], 1.0f);
  }
}

// ---------------- conv2 ----------------
__global__ void k_xw2(const float* __restrict__ x1, const float* __restrict__ W2,
                      float* __restrict__ h20) {
  int t = blockIdx.x * blockDim.x + threadIdx.x;
  if (t >= KK1 * CC) return;
  int node = t / CC;
  int o = t - node * CC;
  float acc = 0.f;
#pragma unroll
  for (int k = 0; k < HH; ++k) acc += x1[node * HH + k] * W2[k * CC + o];
  h20[t] = acc;
}

template <int D, bool RELU>
__global__ void k_combine(const float* __restrict__ h0, const float* __restrict__ dinv,
                          const float* __restrict__ b, float* __restrict__ agg, int n) {
  int i = blockIdx.x * blockDim.x + threadIdx.x;
  if (i >= n * D) return;
  int node = i / D;
  int k = i - node * D;
  float di = dinv[node];
  float v = agg[i] + h0[i] * di * di + b[k];
  if (RELU) v = v > 0.f ? v : 0.f;
  agg[i] = v;
}

template <int D>
__global__ void k_score_init(const float* __restrict__ h, const float* __restrict__ wroot,
                             const float* __restrict__ wrel, const float* __restrict__ bp,
                             int n, float* __restrict__ score, float* __restrict__ hrel) {
  int i = blockIdx.x * blockDim.x + threadIdx.x;
  if (i >= n) return;
  float sr = 0.f, sl = 0.f;
#pragma unroll
  for (int k = 0; k < D; ++k) {
    float v = h[i * D + k];
    sr += v * wroot[k];
    sl += v * wrel[k];
  }
  score[i] = sr + bp[0];
  hrel[i] = sl;
}

__global__ void k_agg2(const float* __restrict__ h20, const float* __restrict__ dinv,
                       const int* __restrict__ es, const int* __restrict__ ed,
                       const int* __restrict__ ecnt, float* __restrict__ agg) {
  int e = blockIdx.x * blockDim.x + threadIdx.x;
  if (e >= *ecnt) return;
  int s = es[e], d = ed[e];
  float norm = dinv[s] * dinv[d];
#pragma unroll
  for (int k = 0; k < CC; ++k)
    atomicAdd(&agg[d * CC + k], h20[s * CC + k] * norm);
}

__global__ void k_score_edges2(const int* __restrict__ es, const int* __restrict__ ed,
                               const int* __restrict__ ecnt,
                               const float* __restrict__ hrel, float* __restrict__ score) {
  int e = blockIdx.x * blockDim.x + threadIdx.x;
  if (e < *ecnt) atomicAdd(&score[ed[e]], hrel[es[e]]);
}

// pool2 selection folded into output accumulator; wave+LDS reduce, 10 atomics/block
__global__ __launch_bounds__(256) void k_final_accum(const float* __restrict__ score,
                                                     const float* __restrict__ h2,
                                                     SelState* st, float* __restrict__ acc) {
  int i = blockIdx.x * blockDim.x + threadIdx.x;
  float tv = 0.f;
  if (i < KK1) {
    float sc = score[i];
    unsigned key = fkey(sc);
    unsigned T = st->prefix;
    bool keep = false;
    if (key > T) {
      keep = true;
    } else if (key == T) {
      unsigned p = atomicAdd(&st->ctr_eq, 1u);
      keep = (p < st->kcur);
    }
    if (keep) tv = tanhf(sc);
  }
  __shared__ float sacc[CC];
  if (threadIdx.x < CC) sacc[threadIdx.x] = 0.f;
  __syncthreads();
#pragma unroll
  for (int c = 0; c < CC; ++c) {
    float v = (i < KK1 && tv != 0.f) ? h2[i * CC + c] * tv : 0.f;
#pragma unroll
    for (int m = 32; m; m >>= 1) v += __shfl_xor(v, m, 64);
    if ((threadIdx.x & 63) == 0) atomicAdd(&sacc[c], v);
  }
  __syncthreads();
  if (threadIdx.x < CC) atomicAdd(&acc[threadIdx.x], sacc[threadIdx.x]);
}

__global__ void k_final(const float* __restrict__ acc, float* __restrict__ out) {
  if (threadIdx.x != 0 || blockIdx.x != 0) return;
  float v[CC];
  float m = -1e30f;
#pragma unroll
  for (int c = 0; c < CC; ++c) {
    v[c] = acc[c] / (float)KK2;
    if (v[c] > m) m = v[c];
  }
  float s = 0.f;
#pragma unroll
  for (int c = 0; c < CC; ++c) s += expf(v[c] - m);
  float l = logf(s);
#pragma unroll
  for (int c = 0; c < CC; ++c) out[c] = v[c] - m - l;
}

// ---------------- driver ----------------
extern "C" void kernel_launch(void* const* d_in, const int* in_sizes, int n_in,
                              void* d_out, int out_size, void* d_ws, size_t ws_size,
                              hipStream_t stream) {
  const float* x      = (const float*)d_in[0];
  const int*   esrc   = (const int*)d_in[1];
  const int*   edst   = (const int*)d_in[2];
  const float* W1     = (const float*)d_in[3];
  const float* b1     = (const float*)d_in[4];
  const float* w1root = (const float*)d_in[5];
  const float* w1rel  = (const float*)d_in[6];
  const float* p1b    = (const float*)d_in[7];
  const float* W2     = (const float*)d_in[8];
  const float* b2     = (const float*)d_in[9];
  const float* w2root = (const float*)d_in[10];
  const float* w2rel  = (const float*)d_in[11];
  const float* p2b    = (const float*)d_in[12];
  float* out = (float*)d_out;

  char* w = (char*)d_ws;
  size_t off = 0;
  auto alloc = [&](size_t bytes) -> char* {
    char* p = w + off;
    off += (bytes + 255) & ~(size_t)255;
    return p;
  };
  float* h0     = (float*)alloc((size_t)NN * HH * 4);   // dead after k_conv1 -> carved below
  float* hbuf   = (float*)alloc((size_t)NN * HH * 4);   // h (post-relu)
  float* dinv1  = (float*)alloc((size_t)NN * 4);
  float* hrel1  = (float*)alloc((size_t)NN * 4);
  float* score1 = (float*)alloc((size_t)NN * 4);
  int*   nidx   = (int*)  alloc((size_t)NN * 4);
  int*   csr    = (int*)  alloc((size_t)EE * 4);        // later aliased as es
  int*   rank   = (int*)  alloc((size_t)EE * 4);        // later aliased as ed
  int*   cnt    = (int*)  alloc((size_t)NN * 4);
  int*   rowst  = (int*)  alloc((size_t)(NN + 1) * 4);
  int*   bsum   = (int*)  alloc(512 * 4);
  SelState* st1 = (SelState*)alloc(sizeof(SelState));
  SelState* st2 = (SelState*)alloc(sizeof(SelState));
  int*   ecnt   = (int*)  alloc(256);
  float* acc    = (float*)alloc(256);

  // stage-2 buffers carved out of h0's region (h0 dead after k_conv1)
  size_t off2 = 0;
  auto alloc2 = [&](size_t bytes) -> char* {
    char* p = (char*)h0 + off2;
    off2 += (bytes + 255) & ~(size_t)255;
    return p;
  };
  float* x1     = (float*)alloc2((size_t)KK1 * HH * 4);
  float* h20    = (float*)alloc2((size_t)KK1 * CC * 4);
  float* h2     = (float*)alloc2((size_t)KK1 * CC * 4);
  float* dinv2  = (float*)alloc2((size_t)KK1 * 4);
  float* h2rel  = (float*)alloc2((size_t)KK1 * 4);
  float* score2 = (float*)alloc2((size_t)KK1 * 4);
  int* es = csr;   // csr dead after k_scoreg
  int* ed = rank;  // rank dead after k_scatter

  const int BN  = (NN + 255) / 256;   // 391
  const int BE  = EE / 256;           // 12500
  const int BK1 = (KK1 + 255) / 256;  // 98

  // ---- conv1 GEMM ----
  k_xw1<<<NN / 16, 256, 0, stream>>>(x, W1, h0);

  // ---- CSR build (also produces deg -> dinv1) ----
  hipMemsetAsync(cnt, 0, (size_t)NN * 4, stream);
  k_edge_hist<<<BE, 256, 0, stream>>>(edst, cnt, rank);
  k_scan1<<<BN, 256, 0, stream>>>(cnt, rowst, bsum);
  k_scan2<<<1, 512, 0, stream>>>(bsum, BN);
  k_scan3<<<BN, 256, 0, stream>>>(rowst, bsum, cnt, dinv1);
  k_scatter<<<BE, 256, 0, stream>>>(esrc, edst, rank, rowst, csr);

  // ---- conv1 gather + relu + pool1 score init (fused) ----
  k_conv1<<<NN / 16, 256, 0, stream>>>(h0, dinv1, rowst, csr, b1, w1root, w1rel, p1b,
                                       hbuf, score1, hrel1);
  k_scoreg<<<NN / 32, 256, 0, stream>>>(rowst, csr, hrel1, score1);

  // ---- pool1 top-k (radix select) ----
  k_state_init<<<1, 256, 0, stream>>>(st1, KK1);
  for (int p = 0; p < 4; ++p) {
    k_hist<<<BN, 256, 0, stream>>>(score1, NN, st1, p);
    k_scan<<<1, 1, 0, stream>>>(st1);
  }
  k_select1<<<BN, 256, 0, stream>>>(score1, hbuf, st1, nidx, x1);

  // ---- edge compaction (+deg2 fused) ----
  hipMemsetAsync(ecnt, 0, 4, stream);
  k_fill<<<BK1, 256, 0, stream>>>(dinv2, KK1, 1.0f);
  k_compact<<<BE, 256, 0, stream>>>(esrc, edst, nidx, es, ed, ecnt, dinv2);

  // ---- conv2 ----
  k_xw2<<<(KK1 * CC + 255) / 256, 256, 0, stream>>>(x1, W2, h20);
  k_rsqrt<<<BK1, 256, 0, stream>>>(dinv2, KK1);
  hipMemsetAsync(h2, 0, (size_t)KK1 * CC * 4, stream);
  k_agg2<<<BE, 256, 0, stream>>>(h20, dinv2, es, ed, ecnt, h2);
  k_combine<CC, false><<<(KK1 * CC + 255) / 256, 256, 0, stream>>>(h20, dinv2, b2, h2, KK1);

  // ---- pool2 score ----
  k_score_init<CC><<<BK1, 256, 0, stream>>>(h2, w2root, w2rel, p2b, KK1, score2, h2rel);
  k_score_edges2<<<BE, 256, 0, stream>>>(es, ed, ecnt, h2rel, score2);

  // ---- pool2 top-k + mean + log_softmax ----
  k_state_init<<<1, 256, 0, stream>>>(st2, KK2);
  for (int p = 0; p < 4; ++p) {
    k_hist<<<BK1, 256, 0, stream>>>(score2, KK1, st2, p);
    k_scan<<<1, 1, 0, stream>>>(st2);
  }
  hipMemsetAsync(acc, 0, CC * 4, stream);
  k_final_accum<<<BK1, 256, 0, stream>>>(score2, h2, st2, acc);
  k_final<<<1, 64, 0, stream>>>(acc, out);
}

// Round 5
// 624.685 us; speedup vs baseline: 2.5138x; 1.4140x over previous
//
#include <hip/hip_runtime.h>
#include <math.h>

#define NN 100000
#define EE 3200000
#define FF 128
#define HH 16
#define CC 10
#define KK1 25000
#define KK2 6250

struct SelState {
  unsigned prefix;
  unsigned kcur;
  unsigned ctr_gt;
  unsigned ctr_eq;
  unsigned hist[256];
};

__device__ __forceinline__ unsigned fkey(float f) {
  unsigned u = __float_as_uint(f);
  return (u & 0x80000000u) ? ~u : (u | 0x80000000u);
}

// ---------------- conv1 GEMM: h0 = x @ W1  ([N,128] @ [128,16]) ----------------
__global__ __launch_bounds__(256) void k_xw1(const float* __restrict__ x,
                                             const float* __restrict__ W1,
                                             float* __restrict__ h0) {
  __shared__ float sW[FF * HH];     // 8 KB
  __shared__ float sx[16][FF];      // 8 KB
  int t = threadIdx.x;
  for (int i = t; i < FF * HH; i += 256) sW[i] = W1[i];
  int base = blockIdx.x * 16;
  for (int i = t; i < 16 * FF; i += 256) {
    int r = i >> 7, c = i & 127;
    int node = base + r;
    sx[r][c] = (node < NN) ? x[(size_t)node * FF + c] : 0.f;
  }
  __syncthreads();
  int r = t >> 4;   // node in tile
  int o = t & 15;   // output col
  float acc = 0.f;
#pragma unroll
  for (int k = 0; k < FF; ++k) acc += sx[r][k] * sW[k * HH + o];
  int node = base + r;
  if (node < NN) h0[node * HH + o] = acc;
}

// ---------------- CSR build (by dst) ----------------
// returning atomic: rank[e] = old count (edge's slot within its dst segment)
__global__ void k_edge_hist(const int* __restrict__ dst, int* __restrict__ cnt,
                            int* __restrict__ rank) {
  int e = blockIdx.x * 256 + threadIdx.x;
  if (e < EE) rank[e] = atomicAdd(&cnt[dst[e]], 1);
}

__global__ __launch_bounds__(256) void k_scan1(const int* __restrict__ cnt,
                                               int* __restrict__ rowstart,
                                               int* __restrict__ bsum) {
  __shared__ int s[256];
  int t = threadIdx.x;
  int i = blockIdx.x * 256 + t;
  int v = (i < NN) ? cnt[i] : 0;
  s[t] = v;
  __syncthreads();
  for (int off = 1; off < 256; off <<= 1) {
    int u = (t >= off) ? s[t - off] : 0;
    __syncthreads();
    s[t] += u;
    __syncthreads();
  }
  if (i < NN) rowstart[i] = s[t] - v;   // exclusive
  if (t == 255) bsum[blockIdx.x] = s[255];
}

__global__ __launch_bounds__(512) void k_scan2(int* __restrict__ bsum, int n) {
  __shared__ int s[512];
  int t = threadIdx.x;
  int v = (t < n) ? bsum[t] : 0;
  s[t] = v;
  __syncthreads();
  for (int off = 1; off < 512; off <<= 1) {
    int u = (t >= off) ? s[t - off] : 0;
    __syncthreads();
    s[t] += u;
    __syncthreads();
  }
  if (t < n) bsum[t] = s[t] - v;        // exclusive
}

__global__ void k_scan3(int* __restrict__ rowstart, const int* __restrict__ bsum,
                        const int* __restrict__ cnt, float* __restrict__ dinv) {
  int i = blockIdx.x * 256 + threadIdx.x;
  if (i == 0) rowstart[NN] = EE;
  if (i < NN) {
    rowstart[i] += bsum[blockIdx.x];
    dinv[i] = rsqrtf((float)cnt[i] + 1.0f);   // deg = cnt + 1 (self-loop)
  }
}

__global__ void k_scatter(const int* __restrict__ src, const int* __restrict__ dst,
                          const int* __restrict__ rank, const int* __restrict__ rowstart,
                          int* __restrict__ csr) {
  int e = blockIdx.x * 256 + threadIdx.x;
  if (e < EE) csr[rowstart[dst[e]] + rank[e]] = src[e];
}

// ---------------- conv1 gather + self-loop + bias + relu + score init ----------------
// 16 threads per node (one per feature); shfl-broadcast csr/dinv; shfl-reduce scores.
__global__ __launch_bounds__(256) void k_conv1(const float* __restrict__ h0,
                                               const float* __restrict__ dinv,
                                               const int* __restrict__ rowstart,
                                               const int* __restrict__ csr,
                                               const float* __restrict__ b1,
                                               const float* __restrict__ wroot,
                                               const float* __restrict__ wrel,
                                               const float* __restrict__ bp,
                                               float* __restrict__ h,
                                               float* __restrict__ score,
                                               float* __restrict__ hrel) {
  int node = blockIdx.x * 16 + (threadIdx.x >> 4);
  int k = threadIdx.x & 15;
  int s0 = rowstart[node], s1 = rowstart[node + 1];
  float acc = 0.f;
  for (int base = s0; base < s1; base += 16) {
    int idx = base + k;
    int sv = (idx < s1) ? csr[idx] : 0;
    float dv = (idx < s1) ? dinv[sv] : 0.f;
    int m = min(16, s1 - base);
    for (int j = 0; j < m; ++j) {
      int s = __shfl(sv, j, 16);
      float d = __shfl(dv, j, 16);
      acc += h0[s * HH + k] * d;      // coalesced 64B row per step
    }
  }
  float di = dinv[node];
  float v = acc * di + h0[node * HH + k] * di * di + b1[k];
  v = v > 0.f ? v : 0.f;
  h[node * HH + k] = v;
  float sr = v * wroot[k];
  float sl = v * wrel[k];
#pragma unroll
  for (int m = 8; m; m >>= 1) {
    sr += __shfl_xor(sr, m, 16);
    sl += __shfl_xor(sl, m, 16);
  }
  if (k == 0) {
    score[node] = sr + bp[0];
    hrel[node] = sl;
  }
}

// score[d] += sum over in-edges of hrel[src]; 8 threads per node, no atomics
__global__ __launch_bounds__(256) void k_scoreg(const int* __restrict__ rowstart,
                                                const int* __restrict__ csr,
                                                const float* __restrict__ hrel,
                                                float* __restrict__ score) {
  int node = blockIdx.x * 32 + (threadIdx.x >> 3);
  int lane = threadIdx.x & 7;
  int s0 = rowstart[node], s1 = rowstart[node + 1];
  float sum = 0.f;
  for (int e = s0 + lane; e < s1; e += 8) sum += hrel[csr[e]];
#pragma unroll
  for (int m = 4; m; m >>= 1) sum += __shfl_xor(sum, m, 8);
  if (lane == 0) score[node] += sum;
}

// ---------------- radix top-k select ----------------
__global__ void k_state_init(SelState* st, int K) {
  if (threadIdx.x == 0) {
    st->prefix = 0;
    st->kcur = (unsigned)K;
    st->ctr_gt = 0;
    st->ctr_eq = 0;
  }
  st->hist[threadIdx.x] = 0;
}

__global__ __launch_bounds__(256) void k_hist(const float* __restrict__ vals, int n,
                                              SelState* st, int pass) {
  __shared__ unsigned sh[256];
  int t = threadIdx.x;
  sh[t] = 0;
  __syncthreads();
  int i = blockIdx.x * 256 + t;
  if (i < n) {
    unsigned key = fkey(vals[i]);
    bool ok = true;
    if (pass != 0) ok = (key >> (32 - 8 * pass)) == st->prefix;
    if (ok) atomicAdd(&sh[(key >> (24 - 8 * pass)) & 255], 1u);
  }
  __syncthreads();
  if (sh[t]) atomicAdd(&st->hist[t], sh[t]);
}

__global__ void k_scan(SelState* st) {
  unsigned kcur = st->kcur;
  unsigned cum = 0;
  int b = 255;
  for (; b >= 0; --b) {
    unsigned c = st->hist[b];
    if (cum + c >= kcur) break;
    cum += c;
  }
  st->prefix = (st->prefix << 8) | (unsigned)b;
  st->kcur = kcur - cum;
  for (int i = 0; i < 256; ++i) st->hist[i] = 0;
}

// pool1 selection: new_idx + orig_of + gather-scale x1 = h[kept]*tanh(score)
__global__ void k_select1(const float* __restrict__ score, const float* __restrict__ h,
                          SelState* st, int* __restrict__ new_idx,
                          int* __restrict__ orig_of, float* __restrict__ x1) {
  int i = blockIdx.x * blockDim.x + threadIdx.x;
  if (i >= NN) return;
  float sc = score[i];
  unsigned key = fkey(sc);
  unsigned T = st->prefix;
  int id = -1;
  if (key > T) {
    id = (int)atomicAdd(&st->ctr_gt, 1u);
  } else if (key == T) {
    unsigned p = atomicAdd(&st->ctr_eq, 1u);
    unsigned kneed = st->kcur;
    if (p < kneed) id = (KK1 - (int)kneed) + (int)p;
  }
  new_idx[i] = id;
  if (id >= 0) {
    orig_of[id] = i;
    float tv = tanhf(sc);
#pragma unroll
    for (int k = 0; k < HH; ++k) x1[id * HH + k] = h[i * HH + k] * tv;
  }
}

// ---------------- conv2 via masked CSR sweeps (no compaction, no atomics) --------
// deg2: count surviving in-edges per kept node; dinv2 = rsqrt(cnt+1)
__global__ __launch_bounds__(256) void k_deg2(const int* __restrict__ orig_of,
                                              const int* __restrict__ rowstart,
                                              const int* __restrict__ csr,
                                              const int* __restrict__ nidx,
                                              float* __restrict__ dinv2) {
  int j = blockIdx.x * 32 + (threadIdx.x >> 3);
  int lane = threadIdx.x & 7;
  if (j >= KK1) return;
  int o = orig_of[j];
  int s0 = rowstart[o], s1 = rowstart[o + 1];
  int c = 0;
  for (int e = s0 + lane; e < s1; e += 8) c += (nidx[csr[e]] >= 0) ? 1 : 0;
#pragma unroll
  for (int m = 4; m; m >>= 1) c += __shfl_xor(c, m, 8);
  if (lane == 0) dinv2[j] = rsqrtf((float)c + 1.0f);
}

// h20 = x1 @ W2 ([K1,16] @ [16,10])
__global__ void k_xw2(const float* __restrict__ x1, const float* __restrict__ W2,
                      float* __restrict__ h20) {
  int t = blockIdx.x * blockDim.x + threadIdx.x;
  if (t >= KK1 * CC) return;
  int node = t / CC;
  int o = t - node * CC;
  float acc = 0.f;
#pragma unroll
  for (int k = 0; k < HH; ++k) acc += x1[node * HH + k] * W2[k * CC + o];
  h20[t] = acc;
}

// conv2 masked gather + self-loop + bias + pool2 score init (fused)
// 16 lanes per kept node; 10 carry features, all 16 load edge indices.
__global__ __launch_bounds__(256) void k_conv2(const float* __restrict__ h20,
                                               const float* __restrict__ dinv2,
                                               const int* __restrict__ orig_of,
                                               const int* __restrict__ rowstart,
                                               const int* __restrict__ csr,
                                               const int* __restrict__ nidx,
                                               const float* __restrict__ b2,
                                               const float* __restrict__ wroot,
                                               const float* __restrict__ wrel,
                                               const float* __restrict__ bp,
                                               float* __restrict__ h2,
                                               float* __restrict__ score2,
                                               float* __restrict__ h2rel) {
  int j = blockIdx.x * 16 + (threadIdx.x >> 4);
  int k = threadIdx.x & 15;
  if (j >= KK1) return;
  int o = orig_of[j];
  int s0 = rowstart[o], s1 = rowstart[o + 1];
  float acc = 0.f;
  for (int base = s0; base < s1; base += 16) {
    int idx = base + k;
    int sv = (idx < s1) ? nidx[csr[idx]] : -1;
    float dv = (sv >= 0) ? dinv2[sv] : 0.f;
    int m = min(16, s1 - base);
    for (int t = 0; t < m; ++t) {
      int s = __shfl(sv, t, 16);
      float d = __shfl(dv, t, 16);
      if (s >= 0 && k < CC) acc += h20[s * CC + k] * d;
    }
  }
  float di = dinv2[j];
  float v = 0.f;
  if (k < CC) {
    v = acc * di + h20[j * CC + k] * di * di + b2[k];
    h2[j * CC + k] = v;
  }
  float sr = (k < CC) ? v * wroot[k] : 0.f;
  float sl = (k < CC) ? v * wrel[k] : 0.f;
#pragma unroll
  for (int m = 8; m; m >>= 1) {
    sr += __shfl_xor(sr, m, 16);
    sl += __shfl_xor(sl, m, 16);
  }
  if (k == 0) {
    score2[j] = sr + bp[0];
    h2rel[j] = sl;
  }
}

// score2[j] += sum over surviving in-edges of h2rel[src]
__global__ __launch_bounds__(256) void k_score2g(const int* __restrict__ orig_of,
                                                 const int* __restrict__ rowstart,
                                                 const int* __restrict__ csr,
                                                 const int* __restrict__ nidx,
                                                 const float* __restrict__ h2rel,
                                                 float* __restrict__ score2) {
  int j = blockIdx.x * 32 + (threadIdx.x >> 3);
  int lane = threadIdx.x & 7;
  if (j >= KK1) return;
  int o = orig_of[j];
  int s0 = rowstart[o], s1 = rowstart[o + 1];
  float sum = 0.f;
  for (int e = s0 + lane; e < s1; e += 8) {
    int s = nidx[csr[e]];
    if (s >= 0) sum += h2rel[s];
  }
#pragma unroll
  for (int m = 4; m; m >>= 1) sum += __shfl_xor(sum, m, 8);
  if (lane == 0) score2[j] += sum;
}

// pool2 selection folded into output accumulator; wave+LDS reduce, 10 atomics/block
__global__ __launch_bounds__(256) void k_final_accum(const float* __restrict__ score,
                                                     const float* __restrict__ h2,
                                                     SelState* st, float* __restrict__ acc) {
  int i = blockIdx.x * blockDim.x + threadIdx.x;
  float tv = 0.f;
  if (i < KK1) {
    float sc = score[i];
    unsigned key = fkey(sc);
    unsigned T = st->prefix;
    bool keep = false;
    if (key > T) {
      keep = true;
    } else if (key == T) {
      unsigned p = atomicAdd(&st->ctr_eq, 1u);
      keep = (p < st->kcur);
    }
    if (keep) tv = tanhf(sc);
  }
  __shared__ float sacc[CC];
  if (threadIdx.x < CC) sacc[threadIdx.x] = 0.f;
  __syncthreads();
#pragma unroll
  for (int c = 0; c < CC; ++c) {
    float v = (i < KK1 && tv != 0.f) ? h2[i * CC + c] * tv : 0.f;
#pragma unroll
    for (int m = 32; m; m >>= 1) v += __shfl_xor(v, m, 64);
    if ((threadIdx.x & 63) == 0) atomicAdd(&sacc[c], v);
  }
  __syncthreads();
  if (threadIdx.x < CC) atomicAdd(&acc[threadIdx.x], sacc[threadIdx.x]);
}

__global__ void k_final(const float* __restrict__ acc, float* __restrict__ out) {
  if (threadIdx.x != 0 || blockIdx.x != 0) return;
  float v[CC];
  float m = -1e30f;
#pragma unroll
  for (int c = 0; c < CC; ++c) {
    v[c] = acc[c] / (float)KK2;
    if (v[c] > m) m = v[c];
  }
  float s = 0.f;
#pragma unroll
  for (int c = 0; c < CC; ++c) s += expf(v[c] - m);
  float l = logf(s);
#pragma unroll
  for (int c = 0; c < CC; ++c) out[c] = v[c] - m - l;
}

// ---------------- driver ----------------
extern "C" void kernel_launch(void* const* d_in, const int* in_sizes, int n_in,
                              void* d_out, int out_size, void* d_ws, size_t ws_size,
                              hipStream_t stream) {
  const float* x      = (const float*)d_in[0];
  const int*   esrc   = (const int*)d_in[1];
  const int*   edst   = (const int*)d_in[2];
  const float* W1     = (const float*)d_in[3];
  const float* b1     = (const float*)d_in[4];
  const float* w1root = (const float*)d_in[5];
  const float* w1rel  = (const float*)d_in[6];
  const float* p1b    = (const float*)d_in[7];
  const float* W2     = (const float*)d_in[8];
  const float* b2     = (const float*)d_in[9];
  const float* w2root = (const float*)d_in[10];
  const float* w2rel  = (const float*)d_in[11];
  const float* p2b    = (const float*)d_in[12];
  float* out = (float*)d_out;

  char* w = (char*)d_ws;
  size_t off = 0;
  auto alloc = [&](size_t bytes) -> char* {
    char* p = w + off;
    off += (bytes + 255) & ~(size_t)255;
    return p;
  };
  float* h0     = (float*)alloc((size_t)NN * HH * 4);   // dead after k_conv1 -> carved below
  float* hbuf   = (float*)alloc((size_t)NN * HH * 4);   // h (post-relu)
  float* dinv1  = (float*)alloc((size_t)NN * 4);
  float* hrel1  = (float*)alloc((size_t)NN * 4);
  float* score1 = (float*)alloc((size_t)NN * 4);
  int*   nidx   = (int*)  alloc((size_t)NN * 4);
  int*   csr    = (int*)  alloc((size_t)EE * 4);
  int*   rank   = (int*)  alloc((size_t)EE * 4);
  int*   cnt    = (int*)  alloc((size_t)NN * 4);
  int*   rowst  = (int*)  alloc((size_t)(NN + 1) * 4);
  int*   bsum   = (int*)  alloc(512 * 4);
  SelState* st1 = (SelState*)alloc(sizeof(SelState));
  SelState* st2 = (SelState*)alloc(sizeof(SelState));
  float* acc    = (float*)alloc(256);

  // stage-2 buffers carved out of h0's region (h0 dead after k_conv1)
  size_t off2 = 0;
  auto alloc2 = [&](size_t bytes) -> char* {
    char* p = (char*)h0 + off2;
    off2 += (bytes + 255) & ~(size_t)255;
    return p;
  };
  float* x1      = (float*)alloc2((size_t)KK1 * HH * 4);
  float* h20     = (float*)alloc2((size_t)KK1 * CC * 4);
  float* h2      = (float*)alloc2((size_t)KK1 * CC * 4);
  float* dinv2   = (float*)alloc2((size_t)KK1 * 4);
  float* h2rel   = (float*)alloc2((size_t)KK1 * 4);
  float* score2  = (float*)alloc2((size_t)KK1 * 4);
  int*   orig_of = (int*)  alloc2((size_t)KK1 * 4);

  const int BN  = (NN + 255) / 256;   // 391
  const int BE  = EE / 256;           // 12500
  const int BK1 = (KK1 + 255) / 256;  // 98

  // ---- conv1 GEMM ----
  k_xw1<<<NN / 16, 256, 0, stream>>>(x, W1, h0);

  // ---- CSR build (also produces deg -> dinv1) ----
  hipMemsetAsync(cnt, 0, (size_t)NN * 4, stream);
  k_edge_hist<<<BE, 256, 0, stream>>>(edst, cnt, rank);
  k_scan1<<<BN, 256, 0, stream>>>(cnt, rowst, bsum);
  k_scan2<<<1, 512, 0, stream>>>(bsum, BN);
  k_scan3<<<BN, 256, 0, stream>>>(rowst, bsum, cnt, dinv1);
  k_scatter<<<BE, 256, 0, stream>>>(esrc, edst, rank, rowst, csr);

  // ---- conv1 gather + relu + pool1 score init (fused) ----
  k_conv1<<<NN / 16, 256, 0, stream>>>(h0, dinv1, rowst, csr, b1, w1root, w1rel, p1b,
                                       hbuf, score1, hrel1);
  k_scoreg<<<NN / 32, 256, 0, stream>>>(rowst, csr, hrel1, score1);

  // ---- pool1 top-k (radix select) ----
  k_state_init<<<1, 256, 0, stream>>>(st1, KK1);
  for (int p = 0; p < 4; ++p) {
    k_hist<<<BN, 256, 0, stream>>>(score1, NN, st1, p);
    k_scan<<<1, 1, 0, stream>>>(st1);
  }
  k_select1<<<BN, 256, 0, stream>>>(score1, hbuf, st1, nidx, orig_of, x1);

  // ---- conv2 via masked CSR sweeps (no edge compaction) ----
  k_deg2<<<(KK1 + 31) / 32, 256, 0, stream>>>(orig_of, rowst, csr, nidx, dinv2);
  k_xw2<<<(KK1 * CC + 255) / 256, 256, 0, stream>>>(x1, W2, h20);
  k_conv2<<<(KK1 + 15) / 16, 256, 0, stream>>>(h20, dinv2, orig_of, rowst, csr, nidx,
                                               b2, w2root, w2rel, p2b, h2, score2, h2rel);
  k_score2g<<<(KK1 + 31) / 32, 256, 0, stream>>>(orig_of, rowst, csr, nidx, h2rel, score2);

  // ---- pool2 top-k + mean + log_softmax ----
  k_state_init<<<1, 256, 0, stream>>>(st2, KK2);
  for (int p = 0; p < 4; ++p) {
    k_hist<<<BK1, 256, 0, stream>>>(score2, KK1, st2, p);
    k_scan<<<1, 1, 0, stream>>>(st2);
  }
  hipMemsetAsync(acc, 0, CC * 4, stream);
  k_final_accum<<<BK1, 256, 0, stream>>>(score2, h2, st2, acc);
  k_final<<<1, 64, 0, stream>>>(acc, out);
}

// Round 6
// 531.106 us; speedup vs baseline: 2.9567x; 1.1762x over previous
//
#include <hip/hip_runtime.h>
#include <math.h>

#define NN 100000
#define EE 3200000
#define FF 128
#define HH 16
#define CC 10
#define KK1 25000
#define KK2 6250

// bucket-sort CSR build parameters
#define NBIN 512        // coarse buckets; used = ceil(NN/256) = 391
#define BUCK_SHIFT 8    // bucket = dst >> 8  (256 nodes per bucket)
#define BUCK_MASK 255
#define ABLK 256        // blocks in passes A and C
#define EPB (EE / ABLK) // 12500 edges per block (exact)
#define NBUCK ((NN + 255) / 256)  // 391

struct SelState {
  unsigned prefix;
  unsigned kcur;
  unsigned ctr_gt;
  unsigned ctr_eq;
  unsigned hist[256];
};

__device__ __forceinline__ unsigned fkey(float f) {
  unsigned u = __float_as_uint(f);
  return (u & 0x80000000u) ? ~u : (u | 0x80000000u);
}

// ---------------- conv1 GEMM: h0 = x @ W1  ([N,128] @ [128,16]) ----------------
__global__ __launch_bounds__(256) void k_xw1(const float* __restrict__ x,
                                             const float* __restrict__ W1,
                                             float* __restrict__ h0) {
  __shared__ float sW[FF * HH];     // 8 KB
  __shared__ float sx[16][FF];      // 8 KB
  int t = threadIdx.x;
  for (int i = t; i < FF * HH; i += 256) sW[i] = W1[i];
  int base = blockIdx.x * 16;
  for (int i = t; i < 16 * FF; i += 256) {
    int r = i >> 7, c = i & 127;
    int node = base + r;
    sx[r][c] = (node < NN) ? x[(size_t)node * FF + c] : 0.f;
  }
  __syncthreads();
  int r = t >> 4;   // node in tile
  int o = t & 15;   // output col
  float acc = 0.f;
#pragma unroll
  for (int k = 0; k < FF; ++k) acc += sx[r][k] * sW[k * HH + o];
  int node = base + r;
  if (node < NN) h0[node * HH + o] = acc;
}

// ---------------- CSR build: atomic-free two-level bucket sort ----------------
// Pass A: per-block LDS coarse histogram, plain coalesced global writes
__global__ __launch_bounds__(256) void k_bhist(const int* __restrict__ dst,
                                               unsigned* __restrict__ Hist) {
  __shared__ unsigned sh[NBIN];
  int t = threadIdx.x;
  for (int i = t; i < NBIN; i += 256) sh[i] = 0;
  __syncthreads();
  int base = blockIdx.x * EPB;
  for (int i = base + t; i < base + EPB; i += 256)
    atomicAdd(&sh[dst[i] >> BUCK_SHIFT], 1u);
  __syncthreads();
  for (int i = t; i < NBIN; i += 256) Hist[blockIdx.x * NBIN + i] = sh[i];
}

// Pass B1: per-bucket exclusive prefix over the ABLK block-histograms (in place),
// bucket totals out. 8 blocks x 64 threads: one thread per bucket.
__global__ __launch_bounds__(64) void k_bcursor(unsigned* __restrict__ Hist,
                                                unsigned* __restrict__ Tot) {
  int bin = blockIdx.x * 64 + threadIdx.x;
  unsigned run = 0;
#pragma unroll 8
  for (int b = 0; b < ABLK; ++b) {
    unsigned c = Hist[b * NBIN + bin];
    Hist[b * NBIN + bin] = run;          // becomes per-block exclusive prefix
    run += c;
  }
  Tot[bin] = run;
}

// Pass B2: exclusive scan of bucket totals -> bucket offsets (NBIN+1 entries)
__global__ __launch_bounds__(512) void k_bscan(const unsigned* __restrict__ Tot,
                                               unsigned* __restrict__ BucketOff) {
  __shared__ unsigned s[NBIN];
  int t = threadIdx.x;
  unsigned v = Tot[t];
  s[t] = v;
  __syncthreads();
  for (int off = 1; off < NBIN; off <<= 1) {
    unsigned u = (t >= off) ? s[t - off] : 0;
    __syncthreads();
    s[t] += u;
    __syncthreads();
  }
  BucketOff[t] = s[t] - v;
  if (t == NBIN - 1) BucketOff[NBIN] = s[t];   // == EE
}

// Pass C: scatter edges into bucket-sorted order via LDS cursors (no global atomics).
// packed = (dst&255)<<17 | src   (src < 2^17)
__global__ __launch_bounds__(256) void k_bscatter(const int* __restrict__ src,
                                                  const int* __restrict__ dst,
                                                  const unsigned* __restrict__ Hist,
                                                  const unsigned* __restrict__ BucketOff,
                                                  unsigned* __restrict__ packed) {
  __shared__ unsigned cur[NBIN];
  int t = threadIdx.x;
  for (int i = t; i < NBIN; i += 256)
    cur[i] = BucketOff[i] + Hist[blockIdx.x * NBIN + i];
  __syncthreads();
  int base = blockIdx.x * EPB;
  for (int i = base + t; i < base + EPB; i += 256) {
    int d = dst[i];
    unsigned pos = atomicAdd(&cur[d >> BUCK_SHIFT], 1u);
    packed[pos] = ((unsigned)(d & BUCK_MASK) << 17) | (unsigned)src[i];
  }
}

// Pass D: one block per bucket. Fine count (256 nodes) -> in-block scan ->
// rowstart + dinv, then LDS-cursor scatter of src into the final CSR.
__global__ __launch_bounds__(256) void k_bfine(const unsigned* __restrict__ packed,
                                               const unsigned* __restrict__ BucketOff,
                                               int* __restrict__ rowstart,
                                               float* __restrict__ dinv,
                                               int* __restrict__ csr) {
  __shared__ unsigned fcnt[256], fpos[256], fcur[256];
  int bin = blockIdx.x;
  int t = threadIdx.x;
  unsigned b0 = BucketOff[bin], b1 = BucketOff[bin + 1];
  fcnt[t] = 0;
  __syncthreads();
  for (unsigned e = b0 + t; e < b1; e += 256)
    atomicAdd(&fcnt[packed[e] >> 17], 1u);
  __syncthreads();
  unsigned v = fcnt[t];
  fpos[t] = v;
  __syncthreads();
  for (int off = 1; off < 256; off <<= 1) {
    unsigned u = (t >= off) ? fpos[t - off] : 0;
    __syncthreads();
    fpos[t] += u;
    __syncthreads();
  }
  unsigned excl = fpos[t] - v;
  fcur[t] = b0 + excl;
  int node = bin * 256 + t;
  if (node < NN) {
    rowstart[node] = (int)(b0 + excl);
    dinv[node] = rsqrtf((float)v + 1.0f);    // deg = cnt + 1 (self-loop)
  }
  if (bin == 0 && t == 0) rowstart[NN] = EE;
  __syncthreads();
  for (unsigned e = b0 + t; e < b1; e += 256) {
    unsigned p = packed[e];
    unsigned pos = atomicAdd(&fcur[p >> 17], 1u);
    csr[pos] = (int)(p & 0x1FFFFu);
  }
}

// ---------------- conv1 gather + self-loop + bias + relu + score init ----------------
__global__ __launch_bounds__(256) void k_conv1(const float* __restrict__ h0,
                                               const float* __restrict__ dinv,
                                               const int* __restrict__ rowstart,
                                               const int* __restrict__ csr,
                                               const float* __restrict__ b1,
                                               const float* __restrict__ wroot,
                                               const float* __restrict__ wrel,
                                               const float* __restrict__ bp,
                                               float* __restrict__ h,
                                               float* __restrict__ score,
                                               float* __restrict__ hrel) {
  int node = blockIdx.x * 16 + (threadIdx.x >> 4);
  int k = threadIdx.x & 15;
  int s0 = rowstart[node], s1 = rowstart[node + 1];
  float acc = 0.f;
  for (int base = s0; base < s1; base += 16) {
    int idx = base + k;
    int sv = (idx < s1) ? csr[idx] : 0;
    float dv = (idx < s1) ? dinv[sv] : 0.f;
    int m = min(16, s1 - base);
    for (int j = 0; j < m; ++j) {
      int s = __shfl(sv, j, 16);
      float d = __shfl(dv, j, 16);
      acc += h0[s * HH + k] * d;      // coalesced 64B row per step
    }
  }
  float di = dinv[node];
  float v = acc * di + h0[node * HH + k] * di * di + b1[k];
  v = v > 0.f ? v : 0.f;
  h[node * HH + k] = v;
  float sr = v * wroot[k];
  float sl = v * wrel[k];
#pragma unroll
  for (int m = 8; m; m >>= 1) {
    sr += __shfl_xor(sr, m, 16);
    sl += __shfl_xor(sl, m, 16);
  }
  if (k == 0) {
    score[node] = sr + bp[0];
    hrel[node] = sl;
  }
}

// score[d] += sum over in-edges of hrel[src]; 8 threads per node, no atomics
__global__ __launch_bounds__(256) void k_scoreg(const int* __restrict__ rowstart,
                                                const int* __restrict__ csr,
                                                const float* __restrict__ hrel,
                                                float* __restrict__ score) {
  int node = blockIdx.x * 32 + (threadIdx.x >> 3);
  int lane = threadIdx.x & 7;
  int s0 = rowstart[node], s1 = rowstart[node + 1];
  float sum = 0.f;
  for (int e = s0 + lane; e < s1; e += 8) sum += hrel[csr[e]];
#pragma unroll
  for (int m = 4; m; m >>= 1) sum += __shfl_xor(sum, m, 8);
  if (lane == 0) score[node] += sum;
}

// ---------------- radix top-k select ----------------
__global__ void k_state_init(SelState* st, int K) {
  if (threadIdx.x == 0) {
    st->prefix = 0;
    st->kcur = (unsigned)K;
    st->ctr_gt = 0;
    st->ctr_eq = 0;
  }
  st->hist[threadIdx.x] = 0;
}

__global__ __launch_bounds__(256) void k_hist(const float* __restrict__ vals, int n,
                                              SelState* st, int pass) {
  __shared__ unsigned sh[256];
  int t = threadIdx.x;
  sh[t] = 0;
  __syncthreads();
  int i = blockIdx.x * 256 + t;
  if (i < n) {
    unsigned key = fkey(vals[i]);
    bool ok = true;
    if (pass != 0) ok = (key >> (32 - 8 * pass)) == st->prefix;
    if (ok) atomicAdd(&sh[(key >> (24 - 8 * pass)) & 255], 1u);
  }
  __syncthreads();
  if (sh[t]) atomicAdd(&st->hist[t], sh[t]);
}

__global__ void k_scan(SelState* st) {
  unsigned kcur = st->kcur;
  unsigned cum = 0;
  int b = 255;
  for (; b >= 0; --b) {
    unsigned c = st->hist[b];
    if (cum + c >= kcur) break;
    cum += c;
  }
  st->prefix = (st->prefix << 8) | (unsigned)b;
  st->kcur = kcur - cum;
  for (int i = 0; i < 256; ++i) st->hist[i] = 0;
}

// pool1 selection: new_idx + orig_of + gather-scale x1 = h[kept]*tanh(score)
__global__ void k_select1(const float* __restrict__ score, const float* __restrict__ h,
                          SelState* st, int* __restrict__ new_idx,
                          int* __restrict__ orig_of, float* __restrict__ x1) {
  int i = blockIdx.x * blockDim.x + threadIdx.x;
  if (i >= NN) return;
  float sc = score[i];
  unsigned key = fkey(sc);
  unsigned T = st->prefix;
  int id = -1;
  if (key > T) {
    id = (int)atomicAdd(&st->ctr_gt, 1u);
  } else if (key == T) {
    unsigned p = atomicAdd(&st->ctr_eq, 1u);
    unsigned kneed = st->kcur;
    if (p < kneed) id = (KK1 - (int)kneed) + (int)p;
  }
  new_idx[i] = id;
  if (id >= 0) {
    orig_of[id] = i;
    float tv = tanhf(sc);
#pragma unroll
    for (int k = 0; k < HH; ++k) x1[id * HH + k] = h[i * HH + k] * tv;
  }
}

// ---------------- conv2 via masked CSR sweeps (no compaction, no atomics) --------
__global__ __launch_bounds__(256) void k_deg2(const int* __restrict__ orig_of,
                                              const int* __restrict__ rowstart,
                                              const int* __restrict__ csr,
                                              const int* __restrict__ nidx,
                                              float* __restrict__ dinv2) {
  int j = blockIdx.x * 32 + (threadIdx.x >> 3);
  int lane = threadIdx.x & 7;
  if (j >= KK1) return;
  int o = orig_of[j];
  int s0 = rowstart[o], s1 = rowstart[o + 1];
  int c = 0;
  for (int e = s0 + lane; e < s1; e += 8) c += (nidx[csr[e]] >= 0) ? 1 : 0;
#pragma unroll
  for (int m = 4; m; m >>= 1) c += __shfl_xor(c, m, 8);
  if (lane == 0) dinv2[j] = rsqrtf((float)c + 1.0f);
}

// h20 = x1 @ W2 ([K1,16] @ [16,10])
__global__ void k_xw2(const float* __restrict__ x1, const float* __restrict__ W2,
                      float* __restrict__ h20) {
  int t = blockIdx.x * blockDim.x + threadIdx.x;
  if (t >= KK1 * CC) return;
  int node = t / CC;
  int o = t - node * CC;
  float acc = 0.f;
#pragma unroll
  for (int k = 0; k < HH; ++k) acc += x1[node * HH + k] * W2[k * CC + o];
  h20[t] = acc;
}

// conv2 masked gather + self-loop + bias + pool2 score init (fused)
__global__ __launch_bounds__(256) void k_conv2(const float* __restrict__ h20,
                                               const float* __restrict__ dinv2,
                                               const int* __restrict__ orig_of,
                                               const int* __restrict__ rowstart,
                                               const int* __restrict__ csr,
                                               const int* __restrict__ nidx,
                                               const float* __restrict__ b2,
                                               const float* __restrict__ wroot,
                                               const float* __restrict__ wrel,
                                               const float* __restrict__ bp,
                                               float* __restrict__ h2,
                                               float* __restrict__ score2,
                                               float* __restrict__ h2rel) {
  int j = blockIdx.x * 16 + (threadIdx.x >> 4);
  int k = threadIdx.x & 15;
  if (j >= KK1) return;
  int o = orig_of[j];
  int s0 = rowstart[o], s1 = rowstart[o + 1];
  float acc = 0.f;
  for (int base = s0; base < s1; base += 16) {
    int idx = base + k;
    int sv = (idx < s1) ? nidx[csr[idx]] : -1;
    float dv = (sv >= 0) ? dinv2[sv] : 0.f;
    int m = min(16, s1 - base);
    for (int t = 0; t < m; ++t) {
      int s = __shfl(sv, t, 16);
      float d = __shfl(dv, t, 16);
      if (s >= 0 && k < CC) acc += h20[s * CC + k] * d;
    }
  }
  float di = dinv2[j];
  float v = 0.f;
  if (k < CC) {
    v = acc * di + h20[j * CC + k] * di * di + b2[k];
    h2[j * CC + k] = v;
  }
  float sr = (k < CC) ? v * wroot[k] : 0.f;
  float sl = (k < CC) ? v * wrel[k] : 0.f;
#pragma unroll
  for (int m = 8; m; m >>= 1) {
    sr += __shfl_xor(sr, m, 16);
    sl += __shfl_xor(sl, m, 16);
  }
  if (k == 0) {
    score2[j] = sr + bp[0];
    h2rel[j] = sl;
  }
}

// score2[j] += sum over surviving in-edges of h2rel[src]
__global__ __launch_bounds__(256) void k_score2g(const int* __restrict__ orig_of,
                                                 const int* __restrict__ rowstart,
                                                 const int* __restrict__ csr,
                                                 const int* __restrict__ nidx,
                                                 const float* __restrict__ h2rel,
                                                 float* __restrict__ score2) {
  int j = blockIdx.x * 32 + (threadIdx.x >> 3);
  int lane = threadIdx.x & 7;
  if (j >= KK1) return;
  int o = orig_of[j];
  int s0 = rowstart[o], s1 = rowstart[o + 1];
  float sum = 0.f;
  for (int e = s0 + lane; e < s1; e += 8) {
    int s = nidx[csr[e]];
    if (s >= 0) sum += h2rel[s];
  }
#pragma unroll
  for (int m = 4; m; m >>= 1) sum += __shfl_xor(sum, m, 8);
  if (lane == 0) score2[j] += sum;
}

// pool2 selection folded into output accumulator; wave+LDS reduce, 10 atomics/block
__global__ __launch_bounds__(256) void k_final_accum(const float* __restrict__ score,
                                                     const float* __restrict__ h2,
                                                     SelState* st, float* __restrict__ acc) {
  int i = blockIdx.x * blockDim.x + threadIdx.x;
  float tv = 0.f;
  if (i < KK1) {
    float sc = score[i];
    unsigned key = fkey(sc);
    unsigned T = st->prefix;
    bool keep = false;
    if (key > T) {
      keep = true;
    } else if (key == T) {
      unsigned p = atomicAdd(&st->ctr_eq, 1u);
      keep = (p < st->kcur);
    }
    if (keep) tv = tanhf(sc);
  }
  __shared__ float sacc[CC];
  if (threadIdx.x < CC) sacc[threadIdx.x] = 0.f;
  __syncthreads();
#pragma unroll
  for (int c = 0; c < CC; ++c) {
    float v = (i < KK1 && tv != 0.f) ? h2[i * CC + c] * tv : 0.f;
#pragma unroll
    for (int m = 32; m; m >>= 1) v += __shfl_xor(v, m, 64);
    if ((threadIdx.x & 63) == 0) atomicAdd(&sacc[c], v);
  }
  __syncthreads();
  if (threadIdx.x < CC) atomicAdd(&acc[threadIdx.x], sacc[threadIdx.x]);
}

__global__ void k_final(const float* __restrict__ acc, float* __restrict__ out) {
  if (threadIdx.x != 0 || blockIdx.x != 0) return;
  float v[CC];
  float m = -1e30f;
#pragma unroll
  for (int c = 0; c < CC; ++c) {
    v[c] = acc[c] / (float)KK2;
    if (v[c] > m) m = v[c];
  }
  float s = 0.f;
#pragma unroll
  for (int c = 0; c < CC; ++c) s += expf(v[c] - m);
  float l = logf(s);
#pragma unroll
  for (int c = 0; c < CC; ++c) out[c] = v[c] - m - l;
}

// ---------------- driver ----------------
extern "C" void kernel_launch(void* const* d_in, const int* in_sizes, int n_in,
                              void* d_out, int out_size, void* d_ws, size_t ws_size,
                              hipStream_t stream) {
  const float* x      = (const float*)d_in[0];
  const int*   esrc   = (const int*)d_in[1];
  const int*   edst   = (const int*)d_in[2];
  const float* W1     = (const float*)d_in[3];
  const float* b1     = (const float*)d_in[4];
  const float* w1root = (const float*)d_in[5];
  const float* w1rel  = (const float*)d_in[6];
  const float* p1b    = (const float*)d_in[7];
  const float* W2     = (const float*)d_in[8];
  const float* b2     = (const float*)d_in[9];
  const float* w2root = (const float*)d_in[10];
  const float* w2rel  = (const float*)d_in[11];
  const float* p2b    = (const float*)d_in[12];
  float* out = (float*)d_out;

  char* w = (char*)d_ws;
  size_t off = 0;
  auto alloc = [&](size_t bytes) -> char* {
    char* p = w + off;
    off += (bytes + 255) & ~(size_t)255;
    return p;
  };
  float*    h0      = (float*)alloc((size_t)NN * HH * 4);   // dead after k_conv1 -> carved below
  float*    hbuf    = (float*)alloc((size_t)NN * HH * 4);   // h (post-relu)
  float*    dinv1   = (float*)alloc((size_t)NN * 4);
  float*    hrel1   = (float*)alloc((size_t)NN * 4);
  float*    score1  = (float*)alloc((size_t)NN * 4);
  int*      nidx    = (int*)  alloc((size_t)NN * 4);
  int*      csr     = (int*)  alloc((size_t)EE * 4);
  unsigned* packed  = (unsigned*)alloc((size_t)EE * 4);
  int*      rowst   = (int*)  alloc((size_t)(NN + 1) * 4);
  unsigned* Hist    = (unsigned*)alloc((size_t)ABLK * NBIN * 4);   // 512 KB
  unsigned* Tot     = (unsigned*)alloc((size_t)NBIN * 4);
  unsigned* BOff    = (unsigned*)alloc((size_t)(NBIN + 1) * 4);
  SelState* st1     = (SelState*)alloc(sizeof(SelState));
  SelState* st2     = (SelState*)alloc(sizeof(SelState));
  float*    acc     = (float*)alloc(256);

  // stage-2 buffers carved out of h0's region (h0 dead after k_conv1)
  size_t off2 = 0;
  auto alloc2 = [&](size_t bytes) -> char* {
    char* p = (char*)h0 + off2;
    off2 += (bytes + 255) & ~(size_t)255;
    return p;
  };
  float* x1      = (float*)alloc2((size_t)KK1 * HH * 4);
  float* h20     = (float*)alloc2((size_t)KK1 * CC * 4);
  float* h2      = (float*)alloc2((size_t)KK1 * CC * 4);
  float* dinv2   = (float*)alloc2((size_t)KK1 * 4);
  float* h2rel   = (float*)alloc2((size_t)KK1 * 4);
  float* score2  = (float*)alloc2((size_t)KK1 * 4);
  int*   orig_of = (int*)  alloc2((size_t)KK1 * 4);

  const int BN  = (NN + 255) / 256;   // 391
  const int BK1 = (KK1 + 255) / 256;  // 98

  // ---- conv1 GEMM ----
  k_xw1<<<NN / 16, 256, 0, stream>>>(x, W1, h0);

  // ---- CSR build: atomic-free bucket sort (also produces rowstart + dinv1) ----
  k_bhist<<<ABLK, 256, 0, stream>>>(edst, Hist);
  k_bcursor<<<NBIN / 64, 64, 0, stream>>>(Hist, Tot);
  k_bscan<<<1, NBIN, 0, stream>>>(Tot, BOff);
  k_bscatter<<<ABLK, 256, 0, stream>>>(esrc, edst, Hist, BOff, packed);
  k_bfine<<<NBUCK, 256, 0, stream>>>(packed, BOff, rowst, dinv1, csr);

  // ---- conv1 gather + relu + pool1 score init (fused) ----
  k_conv1<<<NN / 16, 256, 0, stream>>>(h0, dinv1, rowst, csr, b1, w1root, w1rel, p1b,
                                       hbuf, score1, hrel1);
  k_scoreg<<<NN / 32, 256, 0, stream>>>(rowst, csr, hrel1, score1);

  // ---- pool1 top-k (radix select) ----
  k_state_init<<<1, 256, 0, stream>>>(st1, KK1);
  for (int p = 0; p < 4; ++p) {
    k_hist<<<BN, 256, 0, stream>>>(score1, NN, st1, p);
    k_scan<<<1, 1, 0, stream>>>(st1);
  }
  k_select1<<<BN, 256, 0, stream>>>(score1, hbuf, st1, nidx, orig_of, x1);

  // ---- conv2 via masked CSR sweeps (no edge compaction) ----
  k_deg2<<<(KK1 + 31) / 32, 256, 0, stream>>>(orig_of, rowst, csr, nidx, dinv2);
  k_xw2<<<(KK1 * CC + 255) / 256, 256, 0, stream>>>(x1, W2, h20);
  k_conv2<<<(KK1 + 15) / 16, 256, 0, stream>>>(h20, dinv2, orig_of, rowst, csr, nidx,
                                               b2, w2root, w2rel, p2b, h2, score2, h2rel);
  k_score2g<<<(KK1 + 31) / 32, 256, 0, stream>>>(orig_of, rowst, csr, nidx, h2rel, score2);

  // ---- pool2 top-k + mean + log_softmax ----
  k_state_init<<<1, 256, 0, stream>>>(st2, KK2);
  for (int p = 0; p < 4; ++p) {
    k_hist<<<BK1, 256, 0, stream>>>(score2, KK1, st2, p);
    k_scan<<<1, 1, 0, stream>>>(st2);
  }
  hipMemsetAsync(acc, 0, CC * 4, stream);
  k_final_accum<<<BK1, 256, 0, stream>>>(score2, h2, st2, acc);
  k_final<<<1, 64, 0, stream>>>(acc, out);
}

// Round 7
// 477.898 us; speedup vs baseline: 3.2859x; 1.1113x over previous
//
#include <hip/hip_runtime.h>
#include <math.h>

#define NN 100000
#define EE 3200000
#define FF 128
#define HH 16
#define CC 10
#define PC 12           // padded conv2 feature stride (float4-friendly)
#define KK1 25000
#define KK2 6250

// bucket-sort CSR build parameters
#define NBIN 512        // coarse buckets; used = ceil(NN/256) = 391
#define BUCK_SHIFT 8    // bucket = dst >> 8  (256 nodes per bucket)
#define BUCK_MASK 255
#define ABLK 256        // blocks in passes A and C
#define EPB (EE / ABLK) // 12500 edges per block (exact)
#define NBUCK ((NN + 255) / 256)  // 391

struct SelState {
  unsigned prefix;
  unsigned kcur;
  unsigned ctr_gt;
  unsigned ctr_eq;
  unsigned hist[256];
};

__device__ __forceinline__ unsigned fkey(float f) {
  unsigned u = __float_as_uint(f);
  return (u & 0x80000000u) ? ~u : (u | 0x80000000u);
}

// ---------------- conv1 GEMM: h0 = x @ W1  ([N,128] @ [128,16]) ----------------
__global__ __launch_bounds__(256) void k_xw1(const float* __restrict__ x,
                                             const float* __restrict__ W1,
                                             float* __restrict__ h0) {
  __shared__ float sW[FF * HH];     // 8 KB
  __shared__ float sx[16][FF];      // 8 KB
  int t = threadIdx.x;
  for (int i = t; i < FF * HH; i += 256) sW[i] = W1[i];
  int base = blockIdx.x * 16;
  for (int i = t; i < 16 * FF; i += 256) {
    int r = i >> 7, c = i & 127;
    int node = base + r;
    sx[r][c] = (node < NN) ? x[(size_t)node * FF + c] : 0.f;
  }
  __syncthreads();
  int r = t >> 4;   // node in tile
  int o = t & 15;   // output col
  float acc = 0.f;
#pragma unroll
  for (int k = 0; k < FF; ++k) acc += sx[r][k] * sW[k * HH + o];
  int node = base + r;
  if (node < NN) h0[node * HH + o] = acc;
}

// ---------------- CSR build: atomic-free two-level bucket sort ----------------
__global__ __launch_bounds__(256) void k_bhist(const int* __restrict__ dst,
                                               unsigned* __restrict__ Hist) {
  __shared__ unsigned sh[NBIN];
  int t = threadIdx.x;
  for (int i = t; i < NBIN; i += 256) sh[i] = 0;
  __syncthreads();
  int base = blockIdx.x * EPB;
  for (int i = base + t; i < base + EPB; i += 256)
    atomicAdd(&sh[dst[i] >> BUCK_SHIFT], 1u);
  __syncthreads();
  for (int i = t; i < NBIN; i += 256) Hist[blockIdx.x * NBIN + i] = sh[i];
}

__global__ __launch_bounds__(64) void k_bcursor(unsigned* __restrict__ Hist,
                                                unsigned* __restrict__ Tot) {
  int bin = blockIdx.x * 64 + threadIdx.x;
  unsigned run = 0;
#pragma unroll 8
  for (int b = 0; b < ABLK; ++b) {
    unsigned c = Hist[b * NBIN + bin];
    Hist[b * NBIN + bin] = run;          // becomes per-block exclusive prefix
    run += c;
  }
  Tot[bin] = run;
}

__global__ __launch_bounds__(512) void k_bscan(const unsigned* __restrict__ Tot,
                                               unsigned* __restrict__ BucketOff) {
  __shared__ unsigned s[NBIN];
  int t = threadIdx.x;
  unsigned v = Tot[t];
  s[t] = v;
  __syncthreads();
  for (int off = 1; off < NBIN; off <<= 1) {
    unsigned u = (t >= off) ? s[t - off] : 0;
    __syncthreads();
    s[t] += u;
    __syncthreads();
  }
  BucketOff[t] = s[t] - v;
  if (t == NBIN - 1) BucketOff[NBIN] = s[t];   // == EE
}

// packed = (dst&255)<<17 | src   (src < 2^17)
__global__ __launch_bounds__(256) void k_bscatter(const int* __restrict__ src,
                                                  const int* __restrict__ dst,
                                                  const unsigned* __restrict__ Hist,
                                                  const unsigned* __restrict__ BucketOff,
                                                  unsigned* __restrict__ packed) {
  __shared__ unsigned cur[NBIN];
  int t = threadIdx.x;
  for (int i = t; i < NBIN; i += 256)
    cur[i] = BucketOff[i] + Hist[blockIdx.x * NBIN + i];
  __syncthreads();
  int base = blockIdx.x * EPB;
  for (int i = base + t; i < base + EPB; i += 256) {
    int d = dst[i];
    unsigned pos = atomicAdd(&cur[d >> BUCK_SHIFT], 1u);
    packed[pos] = ((unsigned)(d & BUCK_MASK) << 17) | (unsigned)src[i];
  }
}

__global__ __launch_bounds__(256) void k_bfine(const unsigned* __restrict__ packed,
                                               const unsigned* __restrict__ BucketOff,
                                               int* __restrict__ rowstart,
                                               float* __restrict__ dinv,
                                               int* __restrict__ csr) {
  __shared__ unsigned fcnt[256], fpos[256], fcur[256];
  int bin = blockIdx.x;
  int t = threadIdx.x;
  unsigned b0 = BucketOff[bin], b1 = BucketOff[bin + 1];
  fcnt[t] = 0;
  __syncthreads();
  for (unsigned e = b0 + t; e < b1; e += 256)
    atomicAdd(&fcnt[packed[e] >> 17], 1u);
  __syncthreads();
  unsigned v = fcnt[t];
  fpos[t] = v;
  __syncthreads();
  for (int off = 1; off < 256; off <<= 1) {
    unsigned u = (t >= off) ? fpos[t - off] : 0;
    __syncthreads();
    fpos[t] += u;
    __syncthreads();
  }
  unsigned excl = fpos[t] - v;
  fcur[t] = b0 + excl;
  int node = bin * 256 + t;
  if (node < NN) {
    rowstart[node] = (int)(b0 + excl);
    dinv[node] = rsqrtf((float)v + 1.0f);    // deg = cnt + 1 (self-loop)
  }
  if (bin == 0 && t == 0) rowstart[NN] = EE;
  __syncthreads();
  for (unsigned e = b0 + t; e < b1; e += 256) {
    unsigned p = packed[e];
    unsigned pos = atomicAdd(&fcur[p >> 17], 1u);
    csr[pos] = (int)(p & 0x1FFFFu);
  }
}

// ---------------- conv1: wave-per-node, edge-parallel float4 gather ----------------
// lane = eslot*4 + kq : 16 edges in flight, each loading a 16B quarter-row of h0.
__global__ __launch_bounds__(256) void k_conv1(const float* __restrict__ h0,
                                               const float* __restrict__ dinv,
                                               const int* __restrict__ rowstart,
                                               const int* __restrict__ csr,
                                               const float* __restrict__ b1,
                                               const float* __restrict__ wroot,
                                               const float* __restrict__ wrel,
                                               const float* __restrict__ bp,
                                               float* __restrict__ h,
                                               float* __restrict__ score,
                                               float* __restrict__ hrel) {
  int node = blockIdx.x * 4 + (threadIdx.x >> 6);
  if (node >= NN) return;
  int lane = threadIdx.x & 63;
  int eslot = lane >> 2;          // 0..15
  int kq = lane & 3;              // float4 quarter
  int s0 = rowstart[node], s1 = rowstart[node + 1];
  float ax = 0.f, ay = 0.f, az = 0.f, aw = 0.f;
  for (int base = s0; base < s1; base += 16) {
    int idx = base + eslot;
    bool on = idx < s1;
    int sv = on ? csr[idx] : 0;
    float dv = on ? dinv[sv] : 0.f;
    float4 hv = *(const float4*)(h0 + sv * HH + kq * 4);
    ax += hv.x * dv;
    ay += hv.y * dv;
    az += hv.z * dv;
    aw += hv.w * dv;
  }
#pragma unroll
  for (int m = 4; m <= 32; m <<= 1) {
    ax += __shfl_xor(ax, m);
    ay += __shfl_xor(ay, m);
    az += __shfl_xor(az, m);
    aw += __shfl_xor(aw, m);
  }
  // every lane now has the full sum for its kq
  float di = dinv[node];
  float4 hs = *(const float4*)(h0 + node * HH + kq * 4);
  float vx = ax * di + hs.x * di * di + b1[kq * 4 + 0];
  float vy = ay * di + hs.y * di * di + b1[kq * 4 + 1];
  float vz = az * di + hs.z * di * di + b1[kq * 4 + 2];
  float vw = aw * di + hs.w * di * di + b1[kq * 4 + 3];
  vx = vx > 0.f ? vx : 0.f;
  vy = vy > 0.f ? vy : 0.f;
  vz = vz > 0.f ? vz : 0.f;
  vw = vw > 0.f ? vw : 0.f;
  if (eslot == 0) {
    float4 o4 = make_float4(vx, vy, vz, vw);
    *(float4*)(h + node * HH + kq * 4) = o4;
  }
  float sr = vx * wroot[kq * 4] + vy * wroot[kq * 4 + 1] +
             vz * wroot[kq * 4 + 2] + vw * wroot[kq * 4 + 3];
  float sl = vx * wrel[kq * 4] + vy * wrel[kq * 4 + 1] +
             vz * wrel[kq * 4 + 2] + vw * wrel[kq * 4 + 3];
  sr += __shfl_xor(sr, 1);
  sr += __shfl_xor(sr, 2);
  sl += __shfl_xor(sl, 1);
  sl += __shfl_xor(sl, 2);
  if (lane == 0) {
    score[node] = sr + bp[0];
    hrel[node] = sl;
  }
}

// score[d] += sum over in-edges of hrel[src]; 16 lanes per node, no atomics
__global__ __launch_bounds__(256) void k_scoreg(const int* __restrict__ rowstart,
                                                const int* __restrict__ csr,
                                                const float* __restrict__ hrel,
                                                float* __restrict__ score) {
  int node = blockIdx.x * 16 + (threadIdx.x >> 4);
  if (node >= NN) return;
  int lane = threadIdx.x & 15;
  int s0 = rowstart[node], s1 = rowstart[node + 1];
  float sum = 0.f;
  for (int e = s0 + lane; e < s1; e += 16) sum += hrel[csr[e]];
#pragma unroll
  for (int m = 8; m; m >>= 1) sum += __shfl_xor(sum, m, 16);
  if (lane == 0) score[node] += sum;
}

// ---------------- radix top-k select ----------------
__global__ void k_state_init(SelState* st, int K) {
  if (threadIdx.x == 0) {
    st->prefix = 0;
    st->kcur = (unsigned)K;
    st->ctr_gt = 0;
    st->ctr_eq = 0;
  }
  st->hist[threadIdx.x] = 0;
}

__global__ __launch_bounds__(256) void k_hist(const float* __restrict__ vals, int n,
                                              SelState* st, int pass) {
  __shared__ unsigned sh[256];
  int t = threadIdx.x;
  sh[t] = 0;
  __syncthreads();
  int i = blockIdx.x * 256 + t;
  if (i < n) {
    unsigned key = fkey(vals[i]);
    bool ok = true;
    if (pass != 0) ok = (key >> (32 - 8 * pass)) == st->prefix;
    if (ok) atomicAdd(&sh[(key >> (24 - 8 * pass)) & 255], 1u);
  }
  __syncthreads();
  if (sh[t]) atomicAdd(&st->hist[t], sh[t]);
}

// parallel: suffix-sum over 256 bins, unique winner updates prefix/kcur
__global__ __launch_bounds__(256) void k_scan(SelState* st) {
  __shared__ unsigned s[256];
  int t = threadIdx.x;
  unsigned kcur = st->kcur;      // read BEFORE any update
  unsigned v = st->hist[t];
  s[t] = v;
  __syncthreads();
  for (int off = 1; off < 256; off <<= 1) {
    unsigned u = (t + off < 256) ? s[t + off] : 0;
    __syncthreads();
    s[t] += u;
    __syncthreads();
  }
  unsigned Sme = s[t];
  unsigned Snext = (t < 255) ? s[t + 1] : 0;
  if (Sme >= kcur && Snext < kcur) {
    st->prefix = (st->prefix << 8) | (unsigned)t;
    st->kcur = kcur - Snext;
  }
  st->hist[t] = 0;
}

// pool1 selection: new_idx + orig_of + gather-scale x1 = h[kept]*tanh(score)
__global__ void k_select1(const float* __restrict__ score, const float* __restrict__ h,
                          SelState* st, int* __restrict__ new_idx,
                          int* __restrict__ orig_of, float* __restrict__ x1) {
  int i = blockIdx.x * blockDim.x + threadIdx.x;
  if (i >= NN) return;
  float sc = score[i];
  unsigned key = fkey(sc);
  unsigned T = st->prefix;
  int id = -1;
  if (key > T) {
    id = (int)atomicAdd(&st->ctr_gt, 1u);
  } else if (key == T) {
    unsigned p = atomicAdd(&st->ctr_eq, 1u);
    unsigned kneed = st->kcur;
    if (p < kneed) id = (KK1 - (int)kneed) + (int)p;
  }
  new_idx[i] = id;
  if (id >= 0) {
    orig_of[id] = i;
    float tv = tanhf(sc);
#pragma unroll
    for (int k = 0; k < HH; ++k) x1[id * HH + k] = h[i * HH + k] * tv;
  }
}

// ---------------- conv2 via masked CSR sweeps (no compaction, no atomics) --------
// deg2: 16 lanes per kept node
__global__ __launch_bounds__(256) void k_deg2(const int* __restrict__ orig_of,
                                              const int* __restrict__ rowstart,
                                              const int* __restrict__ csr,
                                              const int* __restrict__ nidx,
                                              float* __restrict__ dinv2) {
  int j = blockIdx.x * 16 + (threadIdx.x >> 4);
  if (j >= KK1) return;
  int lane = threadIdx.x & 15;
  int o = orig_of[j];
  int s0 = rowstart[o], s1 = rowstart[o + 1];
  int c = 0;
  for (int e = s0 + lane; e < s1; e += 16) c += (nidx[csr[e]] >= 0) ? 1 : 0;
#pragma unroll
  for (int m = 8; m; m >>= 1) c += __shfl_xor(c, m, 16);
  if (lane == 0) dinv2[j] = rsqrtf((float)c + 1.0f);
}

// h20 = x1 @ W2, padded to stride PC=12 (cols >= CC are zero)
__global__ void k_xw2(const float* __restrict__ x1, const float* __restrict__ W2,
                      float* __restrict__ h20) {
  int t = blockIdx.x * blockDim.x + threadIdx.x;
  if (t >= KK1 * PC) return;
  int node = t / PC;
  int o = t - node * PC;
  float acc = 0.f;
  if (o < CC) {
#pragma unroll
    for (int k = 0; k < HH; ++k) acc += x1[node * HH + k] * W2[k * CC + o];
  }
  h20[t] = acc;
}

// conv2: wave-per-node, edge-parallel float4 (stride-12 rows; kq=3 lanes inert)
__global__ __launch_bounds__(256) void k_conv2(const float* __restrict__ h20,
                                               const float* __restrict__ dinv2,
                                               const int* __restrict__ orig_of,
                                               const int* __restrict__ rowstart,
                                               const int* __restrict__ csr,
                                               const int* __restrict__ nidx,
                                               const float* __restrict__ b2,
                                               const float* __restrict__ wroot,
                                               const float* __restrict__ wrel,
                                               const float* __restrict__ bp,
                                               float* __restrict__ h2,
                                               float* __restrict__ score2,
                                               float* __restrict__ h2rel) {
  int j = blockIdx.x * 4 + (threadIdx.x >> 6);
  if (j >= KK1) return;
  int lane = threadIdx.x & 63;
  int eslot = lane >> 2;
  int kq = lane & 3;              // kq==3 -> features 12..15 (unused, garbage-safe)
  int o = orig_of[j];
  int s0 = rowstart[o], s1 = rowstart[o + 1];
  float ax = 0.f, ay = 0.f, az = 0.f, aw = 0.f;
  for (int base = s0; base < s1; base += 16) {
    int idx = base + eslot;
    bool on = idx < s1;
    int sv = on ? nidx[csr[idx]] : -1;
    float dv = (sv >= 0) ? dinv2[sv] : 0.f;
    int sva = (sv >= 0) ? sv : 0;
    float4 hv = *(const float4*)(h20 + sva * PC + ((kq < 3) ? kq * 4 : 8));
    if (kq == 3) dv = 0.f;
    ax += hv.x * dv;
    ay += hv.y * dv;
    az += hv.z * dv;
    aw += hv.w * dv;
  }
#pragma unroll
  for (int m = 4; m <= 32; m <<= 1) {
    ax += __shfl_xor(ax, m);
    ay += __shfl_xor(ay, m);
    az += __shfl_xor(az, m);
    aw += __shfl_xor(aw, m);
  }
  float di = dinv2[j];
  int kb = (kq < 3) ? kq * 4 : 8;
  float4 hs = *(const float4*)(h20 + j * PC + kb);
  float bx = (kb + 0 < CC) ? b2[kb + 0] : 0.f;
  float by = (kb + 1 < CC) ? b2[kb + 1] : 0.f;
  float bz = (kb + 2 < CC) ? b2[kb + 2] : 0.f;
  float bw = (kb + 3 < CC) ? b2[kb + 3] : 0.f;
  float vx = ax * di + hs.x * di * di + bx;
  float vy = ay * di + hs.y * di * di + by;
  float vz = az * di + hs.z * di * di + bz;
  float vw = aw * di + hs.w * di * di + bw;
  if (kq == 3) { vx = vy = vz = vw = 0.f; }
  // mask padded cols (kq==2 covers 8..11; 10,11 padded)
  if (kb + 2 >= CC) vz = 0.f;
  if (kb + 3 >= CC) vw = 0.f;
  if (eslot == 0 && kq < 3) {
    float4 o4 = make_float4(vx, vy, vz, vw);
    *(float4*)(h2 + j * PC + kq * 4) = o4;
  }
  float wrx = (kb + 0 < CC) ? wroot[kb + 0] : 0.f;
  float wry = (kb + 1 < CC) ? wroot[kb + 1] : 0.f;
  float wrz = (kb + 2 < CC) ? wroot[kb + 2] : 0.f;
  float wrw = (kb + 3 < CC) ? wroot[kb + 3] : 0.f;
  float wlx = (kb + 0 < CC) ? wrel[kb + 0] : 0.f;
  float wly = (kb + 1 < CC) ? wrel[kb + 1] : 0.f;
  float wlz = (kb + 2 < CC) ? wrel[kb + 2] : 0.f;
  float wlw = (kb + 3 < CC) ? wrel[kb + 3] : 0.f;
  float sr = (kq == 3) ? 0.f : (vx * wrx + vy * wry + vz * wrz + vw * wrw);
  float sl = (kq == 3) ? 0.f : (vx * wlx + vy * wly + vz * wlz + vw * wlw);
  sr += __shfl_xor(sr, 1);
  sr += __shfl_xor(sr, 2);
  sl += __shfl_xor(sl, 1);
  sl += __shfl_xor(sl, 2);
  if (lane == 0) {
    score2[j] = sr + bp[0];
    h2rel[j] = sl;
  }
}

// score2[j] += sum over surviving in-edges of h2rel[src]; 16 lanes per node
__global__ __launch_bounds__(256) void k_score2g(const int* __restrict__ orig_of,
                                                 const int* __restrict__ rowstart,
                                                 const int* __restrict__ csr,
                                                 const int* __restrict__ nidx,
                                                 const float* __restrict__ h2rel,
                                                 float* __restrict__ score2) {
  int j = blockIdx.x * 16 + (threadIdx.x >> 4);
  if (j >= KK1) return;
  int lane = threadIdx.x & 15;
  int o = orig_of[j];
  int s0 = rowstart[o], s1 = rowstart[o + 1];
  float sum = 0.f;
  for (int e = s0 + lane; e < s1; e += 16) {
    int s = nidx[csr[e]];
    if (s >= 0) sum += h2rel[s];
  }
#pragma unroll
  for (int m = 8; m; m >>= 1) sum += __shfl_xor(sum, m, 16);
  if (lane == 0) score2[j] += sum;
}

// pool2 selection folded into output accumulator; wave+LDS reduce, 10 atomics/block
__global__ __launch_bounds__(256) void k_final_accum(const float* __restrict__ score,
                                                     const float* __restrict__ h2,
                                                     SelState* st, float* __restrict__ acc) {
  int i = blockIdx.x * blockDim.x + threadIdx.x;
  float tv = 0.f;
  if (i < KK1) {
    float sc = score[i];
    unsigned key = fkey(sc);
    unsigned T = st->prefix;
    bool keep = false;
    if (key > T) {
      keep = true;
    } else if (key == T) {
      unsigned p = atomicAdd(&st->ctr_eq, 1u);
      keep = (p < st->kcur);
    }
    if (keep) tv = tanhf(sc);
  }
  __shared__ float sacc[CC];
  if (threadIdx.x < CC) sacc[threadIdx.x] = 0.f;
  __syncthreads();
#pragma unroll
  for (int c = 0; c < CC; ++c) {
    float v = (i < KK1 && tv != 0.f) ? h2[i * PC + c] * tv : 0.f;
#pragma unroll
    for (int m = 32; m; m >>= 1) v += __shfl_xor(v, m, 64);
    if ((threadIdx.x & 63) == 0) atomicAdd(&sacc[c], v);
  }
  __syncthreads();
  if (threadIdx.x < CC) atomicAdd(&acc[threadIdx.x], sacc[threadIdx.x]);
}

__global__ void k_final(const float* __restrict__ acc, float* __restrict__ out) {
  if (threadIdx.x != 0 || blockIdx.x != 0) return;
  float v[CC];
  float m = -1e30f;
#pragma unroll
  for (int c = 0; c < CC; ++c) {
    v[c] = acc[c] / (float)KK2;
    if (v[c] > m) m = v[c];
  }
  float s = 0.f;
#pragma unroll
  for (int c = 0; c < CC; ++c) s += expf(v[c] - m);
  float l = logf(s);
#pragma unroll
  for (int c = 0; c < CC; ++c) out[c] = v[c] - m - l;
}

// ---------------- driver ----------------
extern "C" void kernel_launch(void* const* d_in, const int* in_sizes, int n_in,
                              void* d_out, int out_size, void* d_ws, size_t ws_size,
                              hipStream_t stream) {
  const float* x      = (const float*)d_in[0];
  const int*   esrc   = (const int*)d_in[1];
  const int*   edst   = (const int*)d_in[2];
  const float* W1     = (const float*)d_in[3];
  const float* b1     = (const float*)d_in[4];
  const float* w1root = (const float*)d_in[5];
  const float* w1rel  = (const float*)d_in[6];
  const float* p1b    = (const float*)d_in[7];
  const float* W2     = (const float*)d_in[8];
  const float* b2     = (const float*)d_in[9];
  const float* w2root = (const float*)d_in[10];
  const float* w2rel  = (const float*)d_in[11];
  const float* p2b    = (const float*)d_in[12];
  float* out = (float*)d_out;

  char* w = (char*)d_ws;
  size_t off = 0;
  auto alloc = [&](size_t bytes) -> char* {
    char* p = w + off;
    off += (bytes + 255) & ~(size_t)255;
    return p;
  };
  float*    h0      = (float*)alloc((size_t)NN * HH * 4);   // dead after k_conv1 -> carved below
  float*    hbuf    = (float*)alloc((size_t)NN * HH * 4);   // h (post-relu)
  float*    dinv1   = (float*)alloc((size_t)NN * 4);
  float*    hrel1   = (float*)alloc((size_t)NN * 4);
  float*    score1  = (float*)alloc((size_t)NN * 4);
  int*      nidx    = (int*)  alloc((size_t)NN * 4);
  int*      csr     = (int*)  alloc((size_t)EE * 4);
  unsigned* packed  = (unsigned*)alloc((size_t)EE * 4);
  int*      rowst   = (int*)  alloc((size_t)(NN + 1) * 4);
  unsigned* Hist    = (unsigned*)alloc((size_t)ABLK * NBIN * 4);   // 512 KB
  unsigned* Tot     = (unsigned*)alloc((size_t)NBIN * 4);
  unsigned* BOff    = (unsigned*)alloc((size_t)(NBIN + 1) * 4);
  SelState* st1     = (SelState*)alloc(sizeof(SelState));
  SelState* st2     = (SelState*)alloc(sizeof(SelState));
  float*    acc     = (float*)alloc(256);

  // stage-2 buffers carved out of h0's region (h0 dead after k_conv1)
  size_t off2 = 0;
  auto alloc2 = [&](size_t bytes) -> char* {
    char* p = (char*)h0 + off2;
    off2 += (bytes + 255) & ~(size_t)255;
    return p;
  };
  float* x1      = (float*)alloc2((size_t)KK1 * HH * 4);
  float* h20     = (float*)alloc2((size_t)KK1 * PC * 4 + 256);  // +pad for kq-overread
  float* h2      = (float*)alloc2((size_t)KK1 * PC * 4 + 256);
  float* dinv2   = (float*)alloc2((size_t)KK1 * 4);
  float* h2rel   = (float*)alloc2((size_t)KK1 * 4);
  float* score2  = (float*)alloc2((size_t)KK1 * 4);
  int*   orig_of = (int*)  alloc2((size_t)KK1 * 4);

  const int BN  = (NN + 255) / 256;   // 391
  const int BK1 = (KK1 + 255) / 256;  // 98

  // ---- conv1 GEMM ----
  k_xw1<<<NN / 16, 256, 0, stream>>>(x, W1, h0);

  // ---- CSR build: atomic-free bucket sort (also produces rowstart + dinv1) ----
  k_bhist<<<ABLK, 256, 0, stream>>>(edst, Hist);
  k_bcursor<<<NBIN / 64, 64, 0, stream>>>(Hist, Tot);
  k_bscan<<<1, NBIN, 0, stream>>>(Tot, BOff);
  k_bscatter<<<ABLK, 256, 0, stream>>>(esrc, edst, Hist, BOff, packed);
  k_bfine<<<NBUCK, 256, 0, stream>>>(packed, BOff, rowst, dinv1, csr);

  // ---- conv1 gather + relu + pool1 score init (fused) ----
  k_conv1<<<(NN + 3) / 4, 256, 0, stream>>>(h0, dinv1, rowst, csr, b1, w1root, w1rel,
                                            p1b, hbuf, score1, hrel1);
  k_scoreg<<<(NN + 15) / 16, 256, 0, stream>>>(rowst, csr, hrel1, score1);

  // ---- pool1 top-k (radix select) ----
  k_state_init<<<1, 256, 0, stream>>>(st1, KK1);
  for (int p = 0; p < 4; ++p) {
    k_hist<<<BN, 256, 0, stream>>>(score1, NN, st1, p);
    k_scan<<<1, 256, 0, stream>>>(st1);
  }
  k_select1<<<BN, 256, 0, stream>>>(score1, hbuf, st1, nidx, orig_of, x1);

  // ---- conv2 via masked CSR sweeps (no edge compaction) ----
  k_deg2<<<(KK1 + 15) / 16, 256, 0, stream>>>(orig_of, rowst, csr, nidx, dinv2);
  k_xw2<<<(KK1 * PC + 255) / 256, 256, 0, stream>>>(x1, W2, h20);
  k_conv2<<<(KK1 + 3) / 4, 256, 0, stream>>>(h20, dinv2, orig_of, rowst, csr, nidx,
                                             b2, w2root, w2rel, p2b, h2, score2, h2rel);
  k_score2g<<<(KK1 + 15) / 16, 256, 0, stream>>>(orig_of, rowst, csr, nidx, h2rel, score2);

  // ---- pool2 top-k + mean + log_softmax ----
  k_state_init<<<1, 256, 0, stream>>>(st2, KK2);
  for (int p = 0; p < 4; ++p) {
    k_hist<<<BK1, 256, 0, stream>>>(score2, KK1, st2, p);
    k_scan<<<1, 256, 0, stream>>>(st2);
  }
  hipMemsetAsync(acc, 0, CC * 4, stream);
  k_final_accum<<<BK1, 256, 0, stream>>>(score2, h2, st2, acc);
  k_final<<<1, 64, 0, stream>>>(acc, out);
}